// Round 1
// baseline (1182.630 us; speedup 1.0000x reference)
//
#include <hip/hip_runtime.h>
#include <cstdint>
#include <cstddef>

#define IN_DIM 128
#define HID    128
#define NG     20

// ============ CSR build ============
__global__ void zero_ints(int* __restrict__ a, int* __restrict__ b, int n) {
  int i = blockIdx.x * blockDim.x + threadIdx.x;
  if (i < n) { a[i] = 0; b[i] = 0; }
}

__global__ void count_kernel(const int* __restrict__ dst, int* __restrict__ cnt, int E) {
  int e = blockIdx.x * blockDim.x + threadIdx.x;
  if (e < E) atomicAdd(&cnt[dst[e]], 1);
}

// exclusive scan, 256 elems/block
__global__ void scan1(const int* __restrict__ cnt, int* __restrict__ offs,
                      int* __restrict__ bsum, int n) {
  __shared__ int s[256];
  int i = blockIdx.x * 256 + threadIdx.x;
  int v = (i < n) ? cnt[i] : 0;
  s[threadIdx.x] = v;
  __syncthreads();
  for (int o = 1; o < 256; o <<= 1) {
    int t = (threadIdx.x >= o) ? s[threadIdx.x - o] : 0;
    __syncthreads();
    s[threadIdx.x] += t;
    __syncthreads();
  }
  if (i < n) offs[i] = s[threadIdx.x] - v;
  if (threadIdx.x == 255) bsum[blockIdx.x] = s[255];
}

__global__ void scan2(int* __restrict__ bsum, int nb) {
  __shared__ int s[512];
  int v = (threadIdx.x < nb) ? bsum[threadIdx.x] : 0;
  s[threadIdx.x] = v;
  __syncthreads();
  for (int o = 1; o < 512; o <<= 1) {
    int t = (threadIdx.x >= o) ? s[threadIdx.x - o] : 0;
    __syncthreads();
    s[threadIdx.x] += t;
    __syncthreads();
  }
  if (threadIdx.x < nb) bsum[threadIdx.x] = s[threadIdx.x] - v;
}

__global__ void scan3(int* __restrict__ offs, const int* __restrict__ bsum, int n) {
  int i = blockIdx.x * 256 + threadIdx.x;
  if (i < n) offs[i] += bsum[blockIdx.x];
}

__global__ void dis_kernel(const int* __restrict__ cnt, float* __restrict__ dis, int n) {
  int i = blockIdx.x * blockDim.x + threadIdx.x;
  if (i < n) dis[i] = 1.0f / sqrtf((float)cnt[i] + 1.0f);
}

__global__ void fill_kernel(const int* __restrict__ src, const int* __restrict__ dst,
                            const int* __restrict__ offs, int* __restrict__ wcur,
                            const float* __restrict__ dis,
                            int* __restrict__ csrc, float* __restrict__ cw, int E) {
  int e = blockIdx.x * blockDim.x + threadIdx.x;
  if (e < E) {
    int s = src[e], d = dst[e];
    int pos = offs[d] + atomicAdd(&wcur[d], 1);
    csrc[pos] = s;
    cw[pos]  = dis[s] * dis[d];
  }
}

// ============ f32 GEMM: C[M,128] = A[M,128] @ B[128,128] ============
// 64-row tile, 256 threads, 4x8 micro-tile per thread (cols tc*4 and 64+tc*4
// so the ds_read_b128 of B is only 2-way bank-aliased = free).
#define MT 64
#define KC 64
__global__ __launch_bounds__(256) void gemm128(const float* __restrict__ A,
                                               const float* __restrict__ B,
                                               float* __restrict__ C, int M) {
  __shared__ float sA[MT][KC + 4];   // stride 68 floats: 16B-aligned rows, conflict-free
  __shared__ float sB[KC][128];
  int tid = threadIdx.x;
  int m0 = blockIdx.x * MT;
  int tr = tid >> 4;   // 0..15
  int tc = tid & 15;   // 0..15
  float acc[4][8];
#pragma unroll
  for (int i = 0; i < 4; ++i)
#pragma unroll
    for (int j = 0; j < 8; ++j) acc[i][j] = 0.f;

  for (int k0 = 0; k0 < 128; k0 += KC) {
#pragma unroll
    for (int q = 0; q < 4; ++q) {            // A tile: 64 rows x 64 k
      int idx = q * 256 + tid;
      int r = idx >> 4;
      int kk = (idx & 15) << 2;
      float4 v = make_float4(0.f, 0.f, 0.f, 0.f);
      if (m0 + r < M) v = *(const float4*)(A + (size_t)(m0 + r) * 128 + k0 + kk);
      *(float4*)(&sA[r][kk]) = v;
    }
#pragma unroll
    for (int q = 0; q < 8; ++q) {            // B tile: 64 k x 128 n
      int idx = q * 256 + tid;
      int kk = idx >> 5;
      int nn = (idx & 31) << 2;
      *(float4*)(&sB[kk][nn]) = *(const float4*)(B + (size_t)(k0 + kk) * 128 + nn);
    }
    __syncthreads();
#pragma unroll 2
    for (int k = 0; k < KC; k += 4) {
      float4 a0 = *(const float4*)(&sA[tr][k]);
      float4 a1 = *(const float4*)(&sA[tr + 16][k]);
      float4 a2 = *(const float4*)(&sA[tr + 32][k]);
      float4 a3 = *(const float4*)(&sA[tr + 48][k]);
#pragma unroll
      for (int u = 0; u < 4; ++u) {
        float4 blo = *(const float4*)(&sB[k + u][tc * 4]);
        float4 bhi = *(const float4*)(&sB[k + u][64 + tc * 4]);
        float av[4] = {((const float*)&a0)[u], ((const float*)&a1)[u],
                       ((const float*)&a2)[u], ((const float*)&a3)[u]};
        float bl[8] = {blo.x, blo.y, blo.z, blo.w, bhi.x, bhi.y, bhi.z, bhi.w};
#pragma unroll
        for (int i = 0; i < 4; ++i)
#pragma unroll
          for (int j = 0; j < 8; ++j) acc[i][j] = fmaf(av[i], bl[j], acc[i][j]);
      }
    }
    __syncthreads();
  }
#pragma unroll
  for (int i = 0; i < 4; ++i) {
    int r = m0 + tr + 16 * i;
    if (r < M) {
      float4 o0 = make_float4(acc[i][0], acc[i][1], acc[i][2], acc[i][3]);
      float4 o1 = make_float4(acc[i][4], acc[i][5], acc[i][6], acc[i][7]);
      *(float4*)(C + (size_t)r * 128 + tc * 4) = o0;
      *(float4*)(C + (size_t)r * 128 + 64 + tc * 4) = o1;
    }
  }
}

// ============ aggregation: out[i] = relu(sum_e h[src_e]*w_e + h[i]*dis_i^2 + b) ============
// one wave per node; lane handles 2 cols via float2; 4-deep gather unroll for MLP.
__global__ __launch_bounds__(64) void agg_kernel(const float* __restrict__ h,
    const int* __restrict__ csrc, const float* __restrict__ cw,
    const int* __restrict__ offs, const int* __restrict__ cnt,
    const float* __restrict__ dis, const float* __restrict__ bias,
    float* __restrict__ out, int n) {
  int i = blockIdx.x;
  if (i >= n) return;
  int c = threadIdx.x * 2;
  int start = offs[i];
  int m = cnt[i];
  float ax = 0.f, ay = 0.f;
  int e = 0;
  for (; e + 4 <= m; e += 4) {
    int s0 = csrc[start + e];
    int s1 = csrc[start + e + 1];
    int s2 = csrc[start + e + 2];
    int s3 = csrc[start + e + 3];
    float w0 = cw[start + e];
    float w1 = cw[start + e + 1];
    float w2 = cw[start + e + 2];
    float w3 = cw[start + e + 3];
    float2 h0 = *(const float2*)(h + (size_t)s0 * 128 + c);
    float2 h1 = *(const float2*)(h + (size_t)s1 * 128 + c);
    float2 h2 = *(const float2*)(h + (size_t)s2 * 128 + c);
    float2 h3 = *(const float2*)(h + (size_t)s3 * 128 + c);
    ax = fmaf(h0.x, w0, ax); ay = fmaf(h0.y, w0, ay);
    ax = fmaf(h1.x, w1, ax); ay = fmaf(h1.y, w1, ay);
    ax = fmaf(h2.x, w2, ax); ay = fmaf(h2.y, w2, ay);
    ax = fmaf(h3.x, w3, ax); ay = fmaf(h3.y, w3, ay);
  }
  for (; e < m; ++e) {
    int s0 = csrc[start + e];
    float w0 = cw[start + e];
    float2 h0 = *(const float2*)(h + (size_t)s0 * 128 + c);
    ax = fmaf(h0.x, w0, ax); ay = fmaf(h0.y, w0, ay);
  }
  float di = dis[i];
  float d2 = di * di;
  float2 hs = *(const float2*)(h + (size_t)i * 128 + c);
  float2 bv = *(const float2*)(bias + c);
  float vx = fmaf(hs.x, d2, ax) + bv.x;
  float vy = fmaf(hs.y, d2, ay) + bv.y;
  *(float2*)(out + (size_t)i * 128 + c) = make_float2(fmaxf(vx, 0.f), fmaxf(vy, 0.f));
}

// ============ MDN heads: pi=softmax(h@piW+pib), mu, log_sigma ============
// one wave per node, 4 nodes/block; all three [128x20] weights staged in LDS.
__global__ __launch_bounds__(256) void heads_kernel(const float* __restrict__ h,
    const float* __restrict__ piW, const float* __restrict__ muW, const float* __restrict__ lsW,
    const float* __restrict__ pib, const float* __restrict__ mub, const float* __restrict__ lsb,
    float* __restrict__ out, int n) {
  __shared__ float sW[128 * 60];
  __shared__ float sb[60];
  __shared__ float srow[4][128];
  int tid = threadIdx.x;
  for (int idx = tid; idx < 128 * 60; idx += 256) {
    int k = idx / 60, j = idx - k * 60;
    float v;
    if (j < 20)      v = piW[k * 20 + j];
    else if (j < 40) v = muW[k * 20 + (j - 20)];
    else             v = lsW[k * 20 + (j - 40)];
    sW[idx] = v;
  }
  if (tid < 60)
    sb[tid] = (tid < 20) ? pib[tid] : (tid < 40) ? mub[tid - 20] : lsb[tid - 40];

  int wave = tid >> 6, lane = tid & 63;
  int node = blockIdx.x * 4 + wave;
  bool active = node < n;
  if (active) {
    srow[wave][lane]      = h[(size_t)node * 128 + lane];
    srow[wave][lane + 64] = h[(size_t)node * 128 + 64 + lane];
  }
  __syncthreads();

  float acc = 0.f;
  if (active && lane < 60) {
    acc = sb[lane];
#pragma unroll 8
    for (int k = 0; k < 128; ++k) acc = fmaf(srow[wave][k], sW[k * 60 + lane], acc);
  }
  // softmax over lanes 0..19 (width-32 shuffles keep it inside the low half)
  float pv = (active && lane < 20) ? acc : -__builtin_inff();
  float mx = pv;
  for (int o = 16; o > 0; o >>= 1) mx = fmaxf(mx, __shfl_down(mx, o, 32));
  mx = __shfl(mx, 0, 32);
  float ev = (active && lane < 20) ? expf(acc - mx) : 0.f;
  float sm = ev;
  for (int o = 16; o > 0; o >>= 1) sm += __shfl_down(sm, o, 32);
  sm = __shfl(sm, 0, 32);

  if (active) {
    size_t base = (size_t)n * NG;
    if (lane < 20)      out[(size_t)node * NG + lane] = ev / sm;
    else if (lane < 40) out[base + (size_t)node * NG + (lane - 20)] = acc;
    else if (lane < 60) out[2 * base + (size_t)node * NG + (lane - 40)] = acc;
  }
}

extern "C" void kernel_launch(void* const* d_in, const int* in_sizes, int n_in,
                              void* d_out, int out_size, void* d_ws, size_t ws_size,
                              hipStream_t stream) {
  const float* x   = (const float*)d_in[0];
  const int*   ei  = (const int*)d_in[1];
  const float* W1  = (const float*)d_in[2];
  const float* b1  = (const float*)d_in[3];
  const float* W2  = (const float*)d_in[4];
  const float* b2  = (const float*)d_in[5];
  const float* piW = (const float*)d_in[6];
  const float* pib = (const float*)d_in[7];
  const float* muW = (const float*)d_in[8];
  const float* mub = (const float*)d_in[9];
  const float* lsW = (const float*)d_in[10];
  const float* lsb = (const float*)d_in[11];
  float* out = (float*)d_out;

  const int N = in_sizes[0] / IN_DIM;
  const int E = in_sizes[1] / 2;
  const int* src = ei;
  const int* dst = ei + E;

  // workspace layout (~130 MB)
  float* bufA = (float*)d_ws;                       // [N,128] h_pre
  float* bufB = bufA + (size_t)N * HID;             // [N,128] h_out
  int*   cnt  = (int*)(bufB + (size_t)N * HID);     // [N]
  int*   wcur = cnt + N;                            // [N]
  int*   offs = wcur + N;                           // [N]
  int*   bsum = offs + N;                           // [<=512]
  float* dis  = (float*)(bsum + 1024);              // [N]
  int*   csrc = (int*)(dis + N);                    // [E]
  float* cw   = (float*)(csrc + E);                 // [E]

  int nb_scan = (N + 255) / 256;   // 391 <= 512

  zero_ints<<<(N + 255) / 256, 256, 0, stream>>>(cnt, wcur, N);
  count_kernel<<<(E + 255) / 256, 256, 0, stream>>>(dst, cnt, E);
  scan1<<<nb_scan, 256, 0, stream>>>(cnt, offs, bsum, N);
  scan2<<<1, 512, 0, stream>>>(bsum, nb_scan);
  scan3<<<nb_scan, 256, 0, stream>>>(offs, bsum, N);
  dis_kernel<<<(N + 255) / 256, 256, 0, stream>>>(cnt, dis, N);
  fill_kernel<<<(E + 255) / 256, 256, 0, stream>>>(src, dst, offs, wcur, dis, csrc, cw, E);

  // layer 1
  gemm128<<<(N + MT - 1) / MT, 256, 0, stream>>>(x, W1, bufA, N);
  agg_kernel<<<N, 64, 0, stream>>>(bufA, csrc, cw, offs, cnt, dis, b1, bufB, N);
  // layer 2
  gemm128<<<(N + MT - 1) / MT, 256, 0, stream>>>(bufB, W2, bufA, N);
  agg_kernel<<<N, 64, 0, stream>>>(bufA, csrc, cw, offs, cnt, dis, b2, bufB, N);
  // heads
  heads_kernel<<<(N + 3) / 4, 256, 0, stream>>>(bufB, piW, muW, lsW, pib, mub, lsb, out, N);
}

// Round 2
// 1102.473 us; speedup vs baseline: 1.0727x; 1.0727x over previous
//
#include <hip/hip_runtime.h>
#include <cstdint>
#include <cstddef>

#define IN_DIM 128
#define HID    128
#define NG     20

// ============ CSR build ============
__global__ void zero_ints(int* __restrict__ a, int n) {
  int i = blockIdx.x * blockDim.x + threadIdx.x;
  if (i < n) a[i] = 0;
}

__global__ void count_kernel(const int* __restrict__ dst, int* __restrict__ cnt, int E) {
  int e = blockIdx.x * blockDim.x + threadIdx.x;
  if (e < E) atomicAdd(&cnt[dst[e]], 1);
}

// exclusive scan, 256 elems/block
__global__ void scan1(const int* __restrict__ cnt, int* __restrict__ offs,
                      int* __restrict__ bsum, int n) {
  __shared__ int s[256];
  int i = blockIdx.x * 256 + threadIdx.x;
  int v = (i < n) ? cnt[i] : 0;
  s[threadIdx.x] = v;
  __syncthreads();
  for (int o = 1; o < 256; o <<= 1) {
    int t = (threadIdx.x >= o) ? s[threadIdx.x - o] : 0;
    __syncthreads();
    s[threadIdx.x] += t;
    __syncthreads();
  }
  if (i < n) offs[i] = s[threadIdx.x] - v;
  if (threadIdx.x == 255) bsum[blockIdx.x] = s[255];
}

__global__ void scan2(int* __restrict__ bsum, int nb) {
  __shared__ int s[512];
  int v = (threadIdx.x < nb) ? bsum[threadIdx.x] : 0;
  s[threadIdx.x] = v;
  __syncthreads();
  for (int o = 1; o < 512; o <<= 1) {
    int t = (threadIdx.x >= o) ? s[threadIdx.x - o] : 0;
    __syncthreads();
    s[threadIdx.x] += t;
    __syncthreads();
  }
  if (threadIdx.x < nb) bsum[threadIdx.x] = s[threadIdx.x] - v;
}

__global__ void scan3(int* __restrict__ offs, int* __restrict__ wcur,
                      const int* __restrict__ bsum, int n) {
  int i = blockIdx.x * 256 + threadIdx.x;
  if (i < n) {
    int v = offs[i] + bsum[blockIdx.x];
    offs[i] = v;
    wcur[i] = v;   // fill uses wcur directly as the running insert cursor
  }
}

__global__ void dis_kernel(const int* __restrict__ cnt, float* __restrict__ dis, int n) {
  int i = blockIdx.x * blockDim.x + threadIdx.x;
  if (i < n) dis[i] = 1.0f / sqrtf((float)cnt[i] + 1.0f);
}

// one scattered 8B record per edge (src, weight-bits) — single line-touch
__global__ void fill_kernel(const int* __restrict__ src, const int* __restrict__ dst,
                            int* __restrict__ wcur, const float* __restrict__ dis,
                            int2* __restrict__ edges, int E) {
  int e = blockIdx.x * blockDim.x + threadIdx.x;
  if (e < E) {
    int s = src[e], d = dst[e];
    int pos = atomicAdd(&wcur[d], 1);
    edges[pos] = make_int2(s, __float_as_int(dis[s] * dis[d]));
  }
}

// ============ f32 GEMM: C[M,128] = A[M,128] @ B[128,128] ============
#define MT 64
#define KC 64
__global__ __launch_bounds__(256) void gemm128(const float* __restrict__ A,
                                               const float* __restrict__ B,
                                               float* __restrict__ C, int M) {
  __shared__ float sA[MT][KC + 4];
  __shared__ float sB[KC][128];
  int tid = threadIdx.x;
  int m0 = blockIdx.x * MT;
  int tr = tid >> 4;   // 0..15
  int tc = tid & 15;   // 0..15
  float acc[4][8];
#pragma unroll
  for (int i = 0; i < 4; ++i)
#pragma unroll
    for (int j = 0; j < 8; ++j) acc[i][j] = 0.f;

  for (int k0 = 0; k0 < 128; k0 += KC) {
#pragma unroll
    for (int q = 0; q < 4; ++q) {
      int idx = q * 256 + tid;
      int r = idx >> 4;
      int kk = (idx & 15) << 2;
      float4 v = make_float4(0.f, 0.f, 0.f, 0.f);
      if (m0 + r < M) v = *(const float4*)(A + (size_t)(m0 + r) * 128 + k0 + kk);
      *(float4*)(&sA[r][kk]) = v;
    }
#pragma unroll
    for (int q = 0; q < 8; ++q) {
      int idx = q * 256 + tid;
      int kk = idx >> 5;
      int nn = (idx & 31) << 2;
      *(float4*)(&sB[kk][nn]) = *(const float4*)(B + (size_t)(k0 + kk) * 128 + nn);
    }
    __syncthreads();
#pragma unroll 2
    for (int k = 0; k < KC; k += 4) {
      float4 a0 = *(const float4*)(&sA[tr][k]);
      float4 a1 = *(const float4*)(&sA[tr + 16][k]);
      float4 a2 = *(const float4*)(&sA[tr + 32][k]);
      float4 a3 = *(const float4*)(&sA[tr + 48][k]);
#pragma unroll
      for (int u = 0; u < 4; ++u) {
        float4 blo = *(const float4*)(&sB[k + u][tc * 4]);
        float4 bhi = *(const float4*)(&sB[k + u][64 + tc * 4]);
        float av[4] = {((const float*)&a0)[u], ((const float*)&a1)[u],
                       ((const float*)&a2)[u], ((const float*)&a3)[u]};
        float bl[8] = {blo.x, blo.y, blo.z, blo.w, bhi.x, bhi.y, bhi.z, bhi.w};
#pragma unroll
        for (int i = 0; i < 4; ++i)
#pragma unroll
          for (int j = 0; j < 8; ++j) acc[i][j] = fmaf(av[i], bl[j], acc[i][j]);
      }
    }
    __syncthreads();
  }
#pragma unroll
  for (int i = 0; i < 4; ++i) {
    int r = m0 + tr + 16 * i;
    if (r < M) {
      float4 o0 = make_float4(acc[i][0], acc[i][1], acc[i][2], acc[i][3]);
      float4 o1 = make_float4(acc[i][4], acc[i][5], acc[i][6], acc[i][7]);
      *(float4*)(C + (size_t)r * 128 + tc * 4) = o0;
      *(float4*)(C + (size_t)r * 128 + 64 + tc * 4) = o1;
    }
  }
}

// ============ aggregation: out[i] = relu(sum_e h[src_e]*w_e + h[i]*dis_i^2 + b) ============
// 256-thread blocks, 4 nodes/block (one wave each, no barriers) for 32 waves/CU.
__global__ __launch_bounds__(256) void agg_kernel(const float* __restrict__ h,
    const int2* __restrict__ edges,
    const int* __restrict__ offs, const int* __restrict__ cnt,
    const float* __restrict__ dis, const float* __restrict__ bias,
    float* __restrict__ out, int n) {
  int wave = threadIdx.x >> 6;
  int lane = threadIdx.x & 63;
  int i = blockIdx.x * 4 + wave;
  if (i >= n) return;
  int c = lane * 2;
  int start = offs[i];
  int m = cnt[i];
  float ax = 0.f, ay = 0.f;
  int e = 0;
  for (; e + 4 <= m; e += 4) {
    int2 e0 = edges[start + e];
    int2 e1 = edges[start + e + 1];
    int2 e2 = edges[start + e + 2];
    int2 e3 = edges[start + e + 3];
    float2 h0 = *(const float2*)(h + (size_t)e0.x * 128 + c);
    float2 h1 = *(const float2*)(h + (size_t)e1.x * 128 + c);
    float2 h2 = *(const float2*)(h + (size_t)e2.x * 128 + c);
    float2 h3 = *(const float2*)(h + (size_t)e3.x * 128 + c);
    float w0 = __int_as_float(e0.y), w1 = __int_as_float(e1.y);
    float w2 = __int_as_float(e2.y), w3 = __int_as_float(e3.y);
    ax = fmaf(h0.x, w0, ax); ay = fmaf(h0.y, w0, ay);
    ax = fmaf(h1.x, w1, ax); ay = fmaf(h1.y, w1, ay);
    ax = fmaf(h2.x, w2, ax); ay = fmaf(h2.y, w2, ay);
    ax = fmaf(h3.x, w3, ax); ay = fmaf(h3.y, w3, ay);
  }
  for (; e < m; ++e) {
    int2 e0 = edges[start + e];
    float w0 = __int_as_float(e0.y);
    float2 h0 = *(const float2*)(h + (size_t)e0.x * 128 + c);
    ax = fmaf(h0.x, w0, ax); ay = fmaf(h0.y, w0, ay);
  }
  float di = dis[i];
  float d2 = di * di;
  float2 hs = *(const float2*)(h + (size_t)i * 128 + c);
  float2 bv = *(const float2*)(bias + c);
  float vx = fmaf(hs.x, d2, ax) + bv.x;
  float vy = fmaf(hs.y, d2, ay) + bv.y;
  *(float2*)(out + (size_t)i * 128 + c) = make_float2(fmaxf(vx, 0.f), fmaxf(vy, 0.f));
}

// ============ MDN heads ============
__global__ __launch_bounds__(256) void heads_kernel(const float* __restrict__ h,
    const float* __restrict__ piW, const float* __restrict__ muW, const float* __restrict__ lsW,
    const float* __restrict__ pib, const float* __restrict__ mub, const float* __restrict__ lsb,
    float* __restrict__ out, int n) {
  __shared__ float sW[128 * 60];
  __shared__ float sb[60];
  __shared__ float srow[4][128];
  int tid = threadIdx.x;
  for (int idx = tid; idx < 128 * 60; idx += 256) {
    int k = idx / 60, j = idx - k * 60;
    float v;
    if (j < 20)      v = piW[k * 20 + j];
    else if (j < 40) v = muW[k * 20 + (j - 20)];
    else             v = lsW[k * 20 + (j - 40)];
    sW[idx] = v;
  }
  if (tid < 60)
    sb[tid] = (tid < 20) ? pib[tid] : (tid < 40) ? mub[tid - 20] : lsb[tid - 40];

  int wave = tid >> 6, lane = tid & 63;
  int node = blockIdx.x * 4 + wave;
  bool active = node < n;
  if (active) {
    srow[wave][lane]      = h[(size_t)node * 128 + lane];
    srow[wave][lane + 64] = h[(size_t)node * 128 + 64 + lane];
  }
  __syncthreads();

  float acc = 0.f;
  if (active && lane < 60) {
    acc = sb[lane];
#pragma unroll 8
    for (int k = 0; k < 128; ++k) acc = fmaf(srow[wave][k], sW[k * 60 + lane], acc);
  }
  float pv = (active && lane < 20) ? acc : -__builtin_inff();
  float mx = pv;
  for (int o = 16; o > 0; o >>= 1) mx = fmaxf(mx, __shfl_down(mx, o, 32));
  mx = __shfl(mx, 0, 32);
  float ev = (active && lane < 20) ? expf(acc - mx) : 0.f;
  float sm = ev;
  for (int o = 16; o > 0; o >>= 1) sm += __shfl_down(sm, o, 32);
  sm = __shfl(sm, 0, 32);

  if (active) {
    size_t base = (size_t)n * NG;
    if (lane < 20)      out[(size_t)node * NG + lane] = ev / sm;
    else if (lane < 40) out[base + (size_t)node * NG + (lane - 20)] = acc;
    else if (lane < 60) out[2 * base + (size_t)node * NG + (lane - 40)] = acc;
  }
}

extern "C" void kernel_launch(void* const* d_in, const int* in_sizes, int n_in,
                              void* d_out, int out_size, void* d_ws, size_t ws_size,
                              hipStream_t stream) {
  const float* x   = (const float*)d_in[0];
  const int*   ei  = (const int*)d_in[1];
  const float* W1  = (const float*)d_in[2];
  const float* b1  = (const float*)d_in[3];
  const float* W2  = (const float*)d_in[4];
  const float* b2  = (const float*)d_in[5];
  const float* piW = (const float*)d_in[6];
  const float* pib = (const float*)d_in[7];
  const float* muW = (const float*)d_in[8];
  const float* mub = (const float*)d_in[9];
  const float* lsW = (const float*)d_in[10];
  const float* lsb = (const float*)d_in[11];
  float* out = (float*)d_out;

  const int N = in_sizes[0] / IN_DIM;
  const int E = in_sizes[1] / 2;
  const int* src = ei;
  const int* dst = ei + E;

  // workspace layout (~130 MB)
  float* bufA  = (float*)d_ws;                       // [N,128]
  float* bufB  = bufA + (size_t)N * HID;             // [N,128]
  int*   cnt   = (int*)(bufB + (size_t)N * HID);     // [N]
  int*   wcur  = cnt + N;                            // [N]
  int*   offs  = wcur + N;                           // [N]
  int*   bsum  = offs + N;                           // [<=1024]
  float* dis   = (float*)(bsum + 1024);              // [N]
  int2*  edges = (int2*)(dis + N);                   // [E] packed (src, w)

  int nb_scan = (N + 255) / 256;   // 391 <= 512

  zero_ints<<<(N + 255) / 256, 256, 0, stream>>>(cnt, N);
  count_kernel<<<(E + 255) / 256, 256, 0, stream>>>(dst, cnt, E);
  scan1<<<nb_scan, 256, 0, stream>>>(cnt, offs, bsum, N);
  scan2<<<1, 512, 0, stream>>>(bsum, nb_scan);
  scan3<<<nb_scan, 256, 0, stream>>>(offs, wcur, bsum, N);
  dis_kernel<<<(N + 255) / 256, 256, 0, stream>>>(cnt, dis, N);
  fill_kernel<<<(E + 255) / 256, 256, 0, stream>>>(src, dst, wcur, dis, edges, E);

  // layer 1
  gemm128<<<(N + MT - 1) / MT, 256, 0, stream>>>(x, W1, bufA, N);
  agg_kernel<<<(N + 3) / 4, 256, 0, stream>>>(bufA, edges, offs, cnt, dis, b1, bufB, N);
  // layer 2
  gemm128<<<(N + MT - 1) / MT, 256, 0, stream>>>(bufB, W2, bufA, N);
  agg_kernel<<<(N + 3) / 4, 256, 0, stream>>>(bufA, edges, offs, cnt, dis, b2, bufB, N);
  // heads
  heads_kernel<<<(N + 3) / 4, 256, 0, stream>>>(bufB, piW, muW, lsW, pib, mub, lsb, out, N);
}

// Round 3
// 897.924 us; speedup vs baseline: 1.3171x; 1.2278x over previous
//
#include <hip/hip_runtime.h>
#include <hip/hip_fp16.h>
#include <cstdint>
#include <cstddef>

#define IN_DIM 128
#define HID    128
#define NG     20

// ============ CSR build ============
__global__ void zero_ints(int* __restrict__ a, int n) {
  int i = blockIdx.x * blockDim.x + threadIdx.x;
  if (i < n) a[i] = 0;
}

__global__ void count_kernel(const int* __restrict__ dst, int* __restrict__ cnt, int E) {
  int e = blockIdx.x * blockDim.x + threadIdx.x;
  if (e < E) atomicAdd(&cnt[dst[e]], 1);
}

// exclusive scan, 256 elems/block
__global__ void scan1(const int* __restrict__ cnt, int* __restrict__ offs,
                      int* __restrict__ bsum, int n) {
  __shared__ int s[256];
  int i = blockIdx.x * 256 + threadIdx.x;
  int v = (i < n) ? cnt[i] : 0;
  s[threadIdx.x] = v;
  __syncthreads();
  for (int o = 1; o < 256; o <<= 1) {
    int t = (threadIdx.x >= o) ? s[threadIdx.x - o] : 0;
    __syncthreads();
    s[threadIdx.x] += t;
    __syncthreads();
  }
  if (i < n) offs[i] = s[threadIdx.x] - v;
  if (threadIdx.x == 255) bsum[blockIdx.x] = s[255];
}

__global__ void scan2(int* __restrict__ bsum, int nb) {
  __shared__ int s[512];
  int v = (threadIdx.x < nb) ? bsum[threadIdx.x] : 0;
  s[threadIdx.x] = v;
  __syncthreads();
  for (int o = 1; o < 512; o <<= 1) {
    int t = (threadIdx.x >= o) ? s[threadIdx.x - o] : 0;
    __syncthreads();
    s[threadIdx.x] += t;
    __syncthreads();
  }
  if (threadIdx.x < nb) bsum[threadIdx.x] = s[threadIdx.x] - v;
}

__global__ void scan3(int* __restrict__ offs, int* __restrict__ wcur,
                      const int* __restrict__ bsum, int n) {
  int i = blockIdx.x * 256 + threadIdx.x;
  if (i < n) {
    int v = offs[i] + bsum[blockIdx.x];
    offs[i] = v;
    wcur[i] = v;
  }
}

__global__ void dis_kernel(const int* __restrict__ cnt, float* __restrict__ dis, int n) {
  int i = blockIdx.x * blockDim.x + threadIdx.x;
  if (i < n) dis[i] = 1.0f / sqrtf((float)cnt[i] + 1.0f);
}

// one scattered 8B record per edge (src, weight-bits)
__global__ void fill_kernel(const int* __restrict__ src, const int* __restrict__ dst,
                            int* __restrict__ wcur, const float* __restrict__ dis,
                            int2* __restrict__ edges, int E) {
  int e = blockIdx.x * blockDim.x + threadIdx.x;
  if (e < E) {
    int s = src[e], d = dst[e];
    int pos = atomicAdd(&wcur[d], 1);
    edges[pos] = make_int2(s, __float_as_int(dis[s] * dis[d]));
  }
}

// ============ f32 GEMM, f16 output: C16[M,128] = A[M,128] @ B[128,128] ============
#define MT 64
#define KC 64
__global__ __launch_bounds__(256) void gemm128_f16out(const float* __restrict__ A,
                                                      const float* __restrict__ B,
                                                      __half* __restrict__ C, int M) {
  __shared__ float sA[MT][KC + 4];
  __shared__ float sB[KC][128];
  int tid = threadIdx.x;
  int m0 = blockIdx.x * MT;
  int tr = tid >> 4;   // 0..15
  int tc = tid & 15;   // 0..15
  float acc[4][8];
#pragma unroll
  for (int i = 0; i < 4; ++i)
#pragma unroll
    for (int j = 0; j < 8; ++j) acc[i][j] = 0.f;

  for (int k0 = 0; k0 < 128; k0 += KC) {
#pragma unroll
    for (int q = 0; q < 4; ++q) {
      int idx = q * 256 + tid;
      int r = idx >> 4;
      int kk = (idx & 15) << 2;
      float4 v = make_float4(0.f, 0.f, 0.f, 0.f);
      if (m0 + r < M) v = *(const float4*)(A + (size_t)(m0 + r) * 128 + k0 + kk);
      *(float4*)(&sA[r][kk]) = v;
    }
#pragma unroll
    for (int q = 0; q < 8; ++q) {
      int idx = q * 256 + tid;
      int kk = idx >> 5;
      int nn = (idx & 31) << 2;
      *(float4*)(&sB[kk][nn]) = *(const float4*)(B + (size_t)(k0 + kk) * 128 + nn);
    }
    __syncthreads();
#pragma unroll 2
    for (int k = 0; k < KC; k += 4) {
      float4 a0 = *(const float4*)(&sA[tr][k]);
      float4 a1 = *(const float4*)(&sA[tr + 16][k]);
      float4 a2 = *(const float4*)(&sA[tr + 32][k]);
      float4 a3 = *(const float4*)(&sA[tr + 48][k]);
#pragma unroll
      for (int u = 0; u < 4; ++u) {
        float4 blo = *(const float4*)(&sB[k + u][tc * 4]);
        float4 bhi = *(const float4*)(&sB[k + u][64 + tc * 4]);
        float av[4] = {((const float*)&a0)[u], ((const float*)&a1)[u],
                       ((const float*)&a2)[u], ((const float*)&a3)[u]};
        float bl[8] = {blo.x, blo.y, blo.z, blo.w, bhi.x, bhi.y, bhi.z, bhi.w};
#pragma unroll
        for (int i = 0; i < 4; ++i)
#pragma unroll
          for (int j = 0; j < 8; ++j) acc[i][j] = fmaf(av[i], bl[j], acc[i][j]);
      }
    }
    __syncthreads();
  }
#pragma unroll
  for (int i = 0; i < 4; ++i) {
    int r = m0 + tr + 16 * i;
    if (r < M) {
      __half2 p0 = __floats2half2_rn(acc[i][0], acc[i][1]);
      __half2 p1 = __floats2half2_rn(acc[i][2], acc[i][3]);
      __half2 p2 = __floats2half2_rn(acc[i][4], acc[i][5]);
      __half2 p3 = __floats2half2_rn(acc[i][6], acc[i][7]);
      __half2* dst0 = (__half2*)(C + (size_t)r * 128 + tc * 4);
      __half2* dst1 = (__half2*)(C + (size_t)r * 128 + 64 + tc * 4);
      dst0[0] = p0; dst0[1] = p1;
      dst1[0] = p2; dst1[1] = p3;
    }
  }
}

// ============ aggregation (f16 gather, f32 accumulate) ============
// out[i] = relu(sum_e h16[src_e]*w_e + h16[i]*dis_i^2 + b)
__global__ __launch_bounds__(256) void agg_kernel(const __half* __restrict__ h,
    const int2* __restrict__ edges,
    const int* __restrict__ offs, const int* __restrict__ cnt,
    const float* __restrict__ dis, const float* __restrict__ bias,
    float* __restrict__ out, int n) {
  int wave = threadIdx.x >> 6;
  int lane = threadIdx.x & 63;
  int i = blockIdx.x * 4 + wave;
  if (i >= n) return;
  int c = lane * 2;
  int start = offs[i];
  int m = cnt[i];
  float ax = 0.f, ay = 0.f;
  int e = 0;
  for (; e + 4 <= m; e += 4) {
    int2 e0 = edges[start + e];
    int2 e1 = edges[start + e + 1];
    int2 e2 = edges[start + e + 2];
    int2 e3 = edges[start + e + 3];
    float2 h0 = __half22float2(*(const __half2*)(h + (size_t)e0.x * 128 + c));
    float2 h1 = __half22float2(*(const __half2*)(h + (size_t)e1.x * 128 + c));
    float2 h2 = __half22float2(*(const __half2*)(h + (size_t)e2.x * 128 + c));
    float2 h3 = __half22float2(*(const __half2*)(h + (size_t)e3.x * 128 + c));
    float w0 = __int_as_float(e0.y), w1 = __int_as_float(e1.y);
    float w2 = __int_as_float(e2.y), w3 = __int_as_float(e3.y);
    ax = fmaf(h0.x, w0, ax); ay = fmaf(h0.y, w0, ay);
    ax = fmaf(h1.x, w1, ax); ay = fmaf(h1.y, w1, ay);
    ax = fmaf(h2.x, w2, ax); ay = fmaf(h2.y, w2, ay);
    ax = fmaf(h3.x, w3, ax); ay = fmaf(h3.y, w3, ay);
  }
  for (; e < m; ++e) {
    int2 e0 = edges[start + e];
    float w0 = __int_as_float(e0.y);
    float2 h0 = __half22float2(*(const __half2*)(h + (size_t)e0.x * 128 + c));
    ax = fmaf(h0.x, w0, ax); ay = fmaf(h0.y, w0, ay);
  }
  float di = dis[i];
  float d2 = di * di;
  float2 hs = __half22float2(*(const __half2*)(h + (size_t)i * 128 + c));
  float2 bv = *(const float2*)(bias + c);
  float vx = fmaf(hs.x, d2, ax) + bv.x;
  float vy = fmaf(hs.y, d2, ay) + bv.y;
  *(float2*)(out + (size_t)i * 128 + c) = make_float2(fmaxf(vx, 0.f), fmaxf(vy, 0.f));
}

// ============ MDN heads ============
__global__ __launch_bounds__(256) void heads_kernel(const float* __restrict__ h,
    const float* __restrict__ piW, const float* __restrict__ muW, const float* __restrict__ lsW,
    const float* __restrict__ pib, const float* __restrict__ mub, const float* __restrict__ lsb,
    float* __restrict__ out, int n) {
  __shared__ float sW[128 * 60];
  __shared__ float sb[60];
  __shared__ float srow[4][128];
  int tid = threadIdx.x;
  for (int idx = tid; idx < 128 * 60; idx += 256) {
    int k = idx / 60, j = idx - k * 60;
    float v;
    if (j < 20)      v = piW[k * 20 + j];
    else if (j < 40) v = muW[k * 20 + (j - 20)];
    else             v = lsW[k * 20 + (j - 40)];
    sW[idx] = v;
  }
  if (tid < 60)
    sb[tid] = (tid < 20) ? pib[tid] : (tid < 40) ? mub[tid - 20] : lsb[tid - 40];

  int wave = tid >> 6, lane = tid & 63;
  int node = blockIdx.x * 4 + wave;
  bool active = node < n;
  if (active) {
    srow[wave][lane]      = h[(size_t)node * 128 + lane];
    srow[wave][lane + 64] = h[(size_t)node * 128 + 64 + lane];
  }
  __syncthreads();

  float acc = 0.f;
  if (active && lane < 60) {
    acc = sb[lane];
#pragma unroll 8
    for (int k = 0; k < 128; ++k) acc = fmaf(srow[wave][k], sW[k * 60 + lane], acc);
  }
  float pv = (active && lane < 20) ? acc : -__builtin_inff();
  float mx = pv;
  for (int o = 16; o > 0; o >>= 1) mx = fmaxf(mx, __shfl_down(mx, o, 32));
  mx = __shfl(mx, 0, 32);
  float ev = (active && lane < 20) ? expf(acc - mx) : 0.f;
  float sm = ev;
  for (int o = 16; o > 0; o >>= 1) sm += __shfl_down(sm, o, 32);
  sm = __shfl(sm, 0, 32);

  if (active) {
    size_t base = (size_t)n * NG;
    if (lane < 20)      out[(size_t)node * NG + lane] = ev / sm;
    else if (lane < 40) out[base + (size_t)node * NG + (lane - 20)] = acc;
    else if (lane < 60) out[2 * base + (size_t)node * NG + (lane - 40)] = acc;
  }
}

extern "C" void kernel_launch(void* const* d_in, const int* in_sizes, int n_in,
                              void* d_out, int out_size, void* d_ws, size_t ws_size,
                              hipStream_t stream) {
  const float* x   = (const float*)d_in[0];
  const int*   ei  = (const int*)d_in[1];
  const float* W1  = (const float*)d_in[2];
  const float* b1  = (const float*)d_in[3];
  const float* W2  = (const float*)d_in[4];
  const float* b2  = (const float*)d_in[5];
  const float* piW = (const float*)d_in[6];
  const float* pib = (const float*)d_in[7];
  const float* muW = (const float*)d_in[8];
  const float* mub = (const float*)d_in[9];
  const float* lsW = (const float*)d_in[10];
  const float* lsb = (const float*)d_in[11];
  float* out = (float*)d_out;

  const int N = in_sizes[0] / IN_DIM;
  const int E = in_sizes[1] / 2;
  const int* src = ei;
  const int* dst = ei + E;

  // workspace layout
  __half* h16  = (__half*)d_ws;                      // [N,128] f16 pre-agg features
  float* bufB  = (float*)(h16 + (size_t)N * HID);    // [N,128] f32 post-agg
  int*   cnt   = (int*)(bufB + (size_t)N * HID);     // [N]
  int*   wcur  = cnt + N;                            // [N]
  int*   offs  = wcur + N;                           // [N]
  int*   bsum  = offs + N;                           // [<=1024]
  float* dis   = (float*)(bsum + 1024);              // [N]
  int2*  edges = (int2*)(dis + N);                   // [E] packed (src, w)

  int nb_scan = (N + 255) / 256;

  zero_ints<<<(N + 255) / 256, 256, 0, stream>>>(cnt, N);
  count_kernel<<<(E + 255) / 256, 256, 0, stream>>>(dst, cnt, E);
  scan1<<<nb_scan, 256, 0, stream>>>(cnt, offs, bsum, N);
  scan2<<<1, 512, 0, stream>>>(bsum, nb_scan);
  scan3<<<nb_scan, 256, 0, stream>>>(offs, wcur, bsum, N);
  dis_kernel<<<(N + 255) / 256, 256, 0, stream>>>(cnt, dis, N);
  fill_kernel<<<(E + 255) / 256, 256, 0, stream>>>(src, dst, wcur, dis, edges, E);

  // layer 1
  gemm128_f16out<<<(N + MT - 1) / MT, 256, 0, stream>>>(x, W1, h16, N);
  agg_kernel<<<(N + 3) / 4, 256, 0, stream>>>(h16, edges, offs, cnt, dis, b1, bufB, N);
  // layer 2
  gemm128_f16out<<<(N + MT - 1) / MT, 256, 0, stream>>>(bufB, W2, h16, N);
  agg_kernel<<<(N + 3) / 4, 256, 0, stream>>>(h16, edges, offs, cnt, dis, b2, bufB, N);
  // heads
  heads_kernel<<<(N + 3) / 4, 256, 0, stream>>>(bufB, piW, muW, lsW, pib, mub, lsb, out, N);
}

// Round 5
// 876.206 us; speedup vs baseline: 1.3497x; 1.0248x over previous
//
#include <hip/hip_runtime.h>
#include <hip/hip_fp16.h>
#include <cstdint>
#include <cstddef>

#define IN_DIM 128
#define HID    128
#define NG     20
#define BSH    3            // nodes per bucket = 8
#define BNODES (1 << BSH)

// ============ CSR build: XCD-affine two-pass binned counting sort ============
__global__ void zero_ints(int* __restrict__ a, int n) {
  int i = blockIdx.x * blockDim.x + threadIdx.x;
  if (i < n) a[i] = 0;
}

// pass 1: count per (stripe = blockIdx&7, bucket)
__global__ void pass1_count(const int* __restrict__ dst, int* __restrict__ cnt8,
                            int NB, int E) {
  int e = blockIdx.x * 256 + threadIdx.x;
  if (e >= E) return;
  int x = blockIdx.x & 7;
  int b = dst[e] >> BSH;
  atomicAdd(&cnt8[x * NB + b], 1);
}

// 2-level exclusive scan over NB*8 elems in bucket-major (b*8+x) order,
// reading cnt8 stored stripe-major (x*NB+b).
__global__ __launch_bounds__(1024) void scanA(const int* __restrict__ cnt8,
                                              int* __restrict__ boffs8,
                                              int* __restrict__ ssum, int NB) {
  __shared__ int s[1024];
  int NB8 = NB * 8;
  int i = blockIdx.x * 1024 + threadIdx.x;
  int v = 0;
  if (i < NB8) { int b = i >> 3, x = i & 7; v = cnt8[x * NB + b]; }
  s[threadIdx.x] = v;
  __syncthreads();
  for (int o = 1; o < 1024; o <<= 1) {
    int t = (threadIdx.x >= o) ? s[threadIdx.x - o] : 0;
    __syncthreads();
    s[threadIdx.x] += t;
    __syncthreads();
  }
  if (i < NB8) boffs8[i] = s[threadIdx.x] - v;   // block-local exclusive
  if (threadIdx.x == 1023) ssum[blockIdx.x] = s[1023];
}

__global__ __launch_bounds__(1024) void scanB(int* __restrict__ ssum, int nsb) {
  __shared__ int s[1024];
  int v = (threadIdx.x < nsb) ? ssum[threadIdx.x] : 0;
  s[threadIdx.x] = v;
  __syncthreads();
  for (int o = 1; o < 1024; o <<= 1) {
    int t = (threadIdx.x >= o) ? s[threadIdx.x - o] : 0;
    __syncthreads();
    s[threadIdx.x] += t;
    __syncthreads();
  }
  if (threadIdx.x < nsb) ssum[threadIdx.x] = s[threadIdx.x] - v;
}

// add block sums; also initialize the pass-2 cursors (stripe-major layout)
__global__ __launch_bounds__(1024) void scanC(int* __restrict__ boffs8,
                                              int* __restrict__ bcur8,
                                              const int* __restrict__ ssum, int NB) {
  int NB8 = NB * 8;
  int i = blockIdx.x * 1024 + threadIdx.x;
  if (i < NB8) {
    int v = boffs8[i] + ssum[blockIdx.x];
    boffs8[i] = v;
    int b = i >> 3, x = i & 7;
    bcur8[x * NB + b] = v;
  }
}

// pass 2: scatter packed (dst_local<<27 | src) into stripe-affine sub-segments
__global__ void pass2_scatter(const int* __restrict__ src, const int* __restrict__ dst,
                              int* __restrict__ bcur8, int* __restrict__ tmp,
                              int NB, int E) {
  int e = blockIdx.x * 256 + threadIdx.x;
  if (e >= E) return;
  int x = blockIdx.x & 7;
  int s = src[e], d = dst[e];
  int b = d >> BSH;
  int pos = atomicAdd(&bcur8[x * NB + b], 1);
  tmp[pos] = ((d & (BNODES - 1)) << 27) | s;
}

// per-bucket: local count -> cnt/dis/offs, then reorder into final csrc
__global__ __launch_bounds__(64) void order_kernel(const int* __restrict__ tmp,
    const int* __restrict__ boffs8,
    int* __restrict__ csrc, int* __restrict__ cnt, float* __restrict__ dis,
    int* __restrict__ offs, int NB, int N, int E) {
  __shared__ int lcnt[BNODES];
  __shared__ int lcur[BNODES];
  __shared__ int lofs[BNODES];
  int b = blockIdx.x;
  int lane = threadIdx.x;
  int seg_start = boffs8[b * 8];
  int seg_end = (b + 1 < NB) ? boffs8[(b + 1) * 8] : E;
  int m = seg_end - seg_start;
  if (lane < BNODES) lcnt[lane] = 0;
  __syncthreads();
  for (int idx = lane; idx < m; idx += 64)
    atomicAdd(&lcnt[tmp[seg_start + idx] >> 27], 1);
  __syncthreads();
  if (lane == 0) {
    int run = seg_start;
    for (int k = 0; k < BNODES; ++k) { lofs[k] = run; lcur[k] = run; run += lcnt[k]; }
  }
  __syncthreads();
  int node0 = b << BSH;
  if (lane < BNODES) {
    int node = node0 + lane;
    if (node < N) {
      int c = lcnt[lane];
      cnt[node] = c;
      dis[node] = rsqrtf((float)c + 1.0f);
      offs[node] = lofs[lane];
    }
  }
  for (int idx = lane; idx < m; idx += 64) {
    int rec = tmp[seg_start + idx];
    int pos = atomicAdd(&lcur[rec >> 27], 1);
    csrc[pos] = rec & ((1 << 27) - 1);
  }
}

// ============ f32 GEMM, f16 output: C16[M,128] = A[M,128] @ B[128,128] ============
#define MT 64
#define KC 64
__global__ __launch_bounds__(256) void gemm128_f16out(const float* __restrict__ A,
                                                      const float* __restrict__ B,
                                                      __half* __restrict__ C, int M) {
  __shared__ float sA[MT][KC + 4];
  __shared__ float sB[KC][128];
  int tid = threadIdx.x;
  int m0 = blockIdx.x * MT;
  int tr = tid >> 4;   // 0..15
  int tc = tid & 15;   // 0..15
  float acc[4][8];
#pragma unroll
  for (int i = 0; i < 4; ++i)
#pragma unroll
    for (int j = 0; j < 8; ++j) acc[i][j] = 0.f;

  for (int k0 = 0; k0 < 128; k0 += KC) {
#pragma unroll
    for (int q = 0; q < 4; ++q) {
      int idx = q * 256 + tid;
      int r = idx >> 4;
      int kk = (idx & 15) << 2;
      float4 v = make_float4(0.f, 0.f, 0.f, 0.f);
      if (m0 + r < M) v = *(const float4*)(A + (size_t)(m0 + r) * 128 + k0 + kk);
      *(float4*)(&sA[r][kk]) = v;
    }
#pragma unroll
    for (int q = 0; q < 8; ++q) {
      int idx = q * 256 + tid;
      int kk = idx >> 5;
      int nn = (idx & 31) << 2;
      *(float4*)(&sB[kk][nn]) = *(const float4*)(B + (size_t)(k0 + kk) * 128 + nn);
    }
    __syncthreads();
#pragma unroll 2
    for (int k = 0; k < KC; k += 4) {
      float4 a0 = *(const float4*)(&sA[tr][k]);
      float4 a1 = *(const float4*)(&sA[tr + 16][k]);
      float4 a2 = *(const float4*)(&sA[tr + 32][k]);
      float4 a3 = *(const float4*)(&sA[tr + 48][k]);
#pragma unroll
      for (int u = 0; u < 4; ++u) {
        float4 blo = *(const float4*)(&sB[k + u][tc * 4]);
        float4 bhi = *(const float4*)(&sB[k + u][64 + tc * 4]);
        float av[4] = {((const float*)&a0)[u], ((const float*)&a1)[u],
                       ((const float*)&a2)[u], ((const float*)&a3)[u]};
        float bl[8] = {blo.x, blo.y, blo.z, blo.w, bhi.x, bhi.y, bhi.z, bhi.w};
#pragma unroll
        for (int i = 0; i < 4; ++i)
#pragma unroll
          for (int j = 0; j < 8; ++j) acc[i][j] = fmaf(av[i], bl[j], acc[i][j]);
      }
    }
    __syncthreads();
  }
#pragma unroll
  for (int i = 0; i < 4; ++i) {
    int r = m0 + tr + 16 * i;
    if (r < M) {
      __half2 p0 = __floats2half2_rn(acc[i][0], acc[i][1]);
      __half2 p1 = __floats2half2_rn(acc[i][2], acc[i][3]);
      __half2 p2 = __floats2half2_rn(acc[i][4], acc[i][5]);
      __half2 p3 = __floats2half2_rn(acc[i][6], acc[i][7]);
      __half2* dst0 = (__half2*)(C + (size_t)r * 128 + tc * 4);
      __half2* dst1 = (__half2*)(C + (size_t)r * 128 + 64 + tc * 4);
      dst0[0] = p0; dst0[1] = p1;
      dst1[0] = p2; dst1[1] = p3;
    }
  }
}

// ============ aggregation (f16 gather, f32 accumulate, weight on the fly) ============
__global__ __launch_bounds__(256) void agg_kernel(const __half* __restrict__ h,
    const int* __restrict__ csrc,
    const int* __restrict__ offs, const int* __restrict__ cnt,
    const float* __restrict__ dis, const float* __restrict__ bias,
    float* __restrict__ out, int n) {
  int wave = threadIdx.x >> 6;
  int lane = threadIdx.x & 63;
  int i = blockIdx.x * 4 + wave;
  if (i >= n) return;
  int c = lane * 2;
  int start = offs[i];
  int m = cnt[i];
  float di = dis[i];
  float ax = 0.f, ay = 0.f;
  int e = 0;
  for (; e + 4 <= m; e += 4) {
    int s0 = csrc[start + e];
    int s1 = csrc[start + e + 1];
    int s2 = csrc[start + e + 2];
    int s3 = csrc[start + e + 3];
    float w0 = dis[s0] * di, w1 = dis[s1] * di;
    float w2 = dis[s2] * di, w3 = dis[s3] * di;
    float2 h0 = __half22float2(*(const __half2*)(h + (size_t)s0 * 128 + c));
    float2 h1 = __half22float2(*(const __half2*)(h + (size_t)s1 * 128 + c));
    float2 h2 = __half22float2(*(const __half2*)(h + (size_t)s2 * 128 + c));
    float2 h3 = __half22float2(*(const __half2*)(h + (size_t)s3 * 128 + c));
    ax = fmaf(h0.x, w0, ax); ay = fmaf(h0.y, w0, ay);
    ax = fmaf(h1.x, w1, ax); ay = fmaf(h1.y, w1, ay);
    ax = fmaf(h2.x, w2, ax); ay = fmaf(h2.y, w2, ay);
    ax = fmaf(h3.x, w3, ax); ay = fmaf(h3.y, w3, ay);
  }
  for (; e < m; ++e) {
    int s0 = csrc[start + e];
    float w0 = dis[s0] * di;
    float2 h0 = __half22float2(*(const __half2*)(h + (size_t)s0 * 128 + c));
    ax = fmaf(h0.x, w0, ax); ay = fmaf(h0.y, w0, ay);
  }
  float d2 = di * di;
  float2 hs = __half22float2(*(const __half2*)(h + (size_t)i * 128 + c));
  float2 bv = *(const float2*)(bias + c);
  float vx = fmaf(hs.x, d2, ax) + bv.x;
  float vy = fmaf(hs.y, d2, ay) + bv.y;
  *(float2*)(out + (size_t)i * 128 + c) = make_float2(fmaxf(vx, 0.f), fmaxf(vy, 0.f));
}

// ============ MDN heads ============
__global__ __launch_bounds__(256) void heads_kernel(const float* __restrict__ h,
    const float* __restrict__ piW, const float* __restrict__ muW, const float* __restrict__ lsW,
    const float* __restrict__ pib, const float* __restrict__ mub, const float* __restrict__ lsb,
    float* __restrict__ out, int n) {
  __shared__ float sW[128 * 60];
  __shared__ float sb[60];
  __shared__ float srow[4][128];
  int tid = threadIdx.x;
  for (int idx = tid; idx < 128 * 60; idx += 256) {
    int k = idx / 60, j = idx - k * 60;
    float v;
    if (j < 20)      v = piW[k * 20 + j];
    else if (j < 40) v = muW[k * 20 + (j - 20)];
    else             v = lsW[k * 20 + (j - 40)];
    sW[idx] = v;
  }
  if (tid < 60)
    sb[tid] = (tid < 20) ? pib[tid] : (tid < 40) ? mub[tid - 20] : lsb[tid - 40];

  int wave = tid >> 6, lane = tid & 63;
  int node = blockIdx.x * 4 + wave;
  bool active = node < n;
  if (active) {
    srow[wave][lane]      = h[(size_t)node * 128 + lane];
    srow[wave][lane + 64] = h[(size_t)node * 128 + 64 + lane];
  }
  __syncthreads();

  float acc = 0.f;
  if (active && lane < 60) {
    acc = sb[lane];
#pragma unroll 8
    for (int k = 0; k < 128; ++k) acc = fmaf(srow[wave][k], sW[k * 60 + lane], acc);
  }
  float pv = (active && lane < 20) ? acc : -__builtin_inff();
  float mx = pv;
  for (int o = 16; o > 0; o >>= 1) mx = fmaxf(mx, __shfl_down(mx, o, 32));
  mx = __shfl(mx, 0, 32);
  float ev = (active && lane < 20) ? expf(acc - mx) : 0.f;
  float sm = ev;
  for (int o = 16; o > 0; o >>= 1) sm += __shfl_down(sm, o, 32);
  sm = __shfl(sm, 0, 32);

  if (active) {
    size_t base = (size_t)n * NG;
    if (lane < 20)      out[(size_t)node * NG + lane] = ev / sm;
    else if (lane < 40) out[base + (size_t)node * NG + (lane - 20)] = acc;
    else if (lane < 60) out[2 * base + (size_t)node * NG + (lane - 40)] = acc;
  }
}

extern "C" void kernel_launch(void* const* d_in, const int* in_sizes, int n_in,
                              void* d_out, int out_size, void* d_ws, size_t ws_size,
                              hipStream_t stream) {
  const float* x   = (const float*)d_in[0];
  const int*   ei  = (const int*)d_in[1];
  const float* W1  = (const float*)d_in[2];
  const float* b1  = (const float*)d_in[3];
  const float* W2  = (const float*)d_in[4];
  const float* b2  = (const float*)d_in[5];
  const float* piW = (const float*)d_in[6];
  const float* pib = (const float*)d_in[7];
  const float* muW = (const float*)d_in[8];
  const float* mub = (const float*)d_in[9];
  const float* lsW = (const float*)d_in[10];
  const float* lsb = (const float*)d_in[11];
  float* out = (float*)d_out;

  const int N = in_sizes[0] / IN_DIM;
  const int E = in_sizes[1] / 2;
  const int* src = ei;
  const int* dst = ei + E;

  const int NB  = (N + BNODES - 1) >> BSH;   // 12500
  const int NB8 = NB * 8;
  const int nsb = (NB8 + 1023) / 1024;       // 98

  // workspace layout (~92 MB)
  char* p = (char*)d_ws;
  __half* h16 = (__half*)p;                 p += (size_t)N * HID * sizeof(__half);
  // regionR: tmp [E] ints during build, then bufB [N,128] f32 (tmp dead before agg1)
  char* regionR = p;
  size_t szR = (size_t)N * HID * sizeof(float);
  size_t szT = (size_t)E * sizeof(int);
  p += (szR > szT ? szR : szT);
  int*   tmp    = (int*)regionR;
  float* bufB   = (float*)regionR;
  int*   csrc   = (int*)p;                  p += (size_t)E * sizeof(int);
  int*   cnt8   = (int*)p;                  p += (size_t)NB8 * sizeof(int);
  int*   bcur8  = (int*)p;                  p += (size_t)NB8 * sizeof(int);
  int*   boffs8 = (int*)p;                  p += (size_t)NB8 * sizeof(int);
  int*   ssum   = (int*)p;                  p += (size_t)((nsb + 3) & ~3) * sizeof(int);
  int*   cnt    = (int*)p;                  p += (size_t)N * sizeof(int);
  int*   offs   = (int*)p;                  p += (size_t)N * sizeof(int);
  float* dis    = (float*)p;                p += (size_t)N * sizeof(float);

  // ---- CSR build ----
  zero_ints<<<(NB8 + 255) / 256, 256, 0, stream>>>(cnt8, NB8);
  pass1_count<<<(E + 255) / 256, 256, 0, stream>>>(dst, cnt8, NB, E);
  scanA<<<nsb, 1024, 0, stream>>>(cnt8, boffs8, ssum, NB);
  scanB<<<1, 1024, 0, stream>>>(ssum, nsb);
  scanC<<<nsb, 1024, 0, stream>>>(boffs8, bcur8, ssum, NB);
  pass2_scatter<<<(E + 255) / 256, 256, 0, stream>>>(src, dst, bcur8, tmp, NB, E);
  order_kernel<<<NB, 64, 0, stream>>>(tmp, boffs8, csrc, cnt, dis, offs, NB, N, E);

  // ---- layers ----
  gemm128_f16out<<<(N + MT - 1) / MT, 256, 0, stream>>>(x, W1, h16, N);
  agg_kernel<<<(N + 3) / 4, 256, 0, stream>>>(h16, csrc, offs, cnt, dis, b1, bufB, N);
  gemm128_f16out<<<(N + MT - 1) / MT, 256, 0, stream>>>(bufB, W2, h16, N);
  agg_kernel<<<(N + 3) / 4, 256, 0, stream>>>(h16, csrc, offs, cnt, dis, b2, bufB, N);
  heads_kernel<<<(N + 3) / 4, 256, 0, stream>>>(bufB, piW, muW, lsW, pib, mub, lsb, out, N);
}

// Round 6
// 794.579 us; speedup vs baseline: 1.4884x; 1.1027x over previous
//
#include <hip/hip_runtime.h>
#include <hip/hip_fp16.h>
#include <cstdint>
#include <cstddef>

#define IN_DIM 128
#define HID    128
#define NG     20
#define BSH    3            // nodes per bucket = 8
#define BNODES (1 << BSH)

// ============ CSR build: XCD-affine two-pass binned counting sort ============
__global__ void zero_ints(int* __restrict__ a, int n) {
  int i = blockIdx.x * blockDim.x + threadIdx.x;
  if (i < n) a[i] = 0;
}

// pass 1: count per (stripe = blockIdx&7, bucket)
__global__ void pass1_count(const int* __restrict__ dst, int* __restrict__ cnt8,
                            int NB, int E) {
  int e = blockIdx.x * 256 + threadIdx.x;
  if (e >= E) return;
  int x = blockIdx.x & 7;
  int b = dst[e] >> BSH;
  atomicAdd(&cnt8[x * NB + b], 1);
}

// 2-level exclusive scan over NB*8 elems in bucket-major (b*8+x) order,
// reading cnt8 stored stripe-major (x*NB+b).
__global__ __launch_bounds__(1024) void scanA(const int* __restrict__ cnt8,
                                              int* __restrict__ boffs8,
                                              int* __restrict__ ssum, int NB) {
  __shared__ int s[1024];
  int NB8 = NB * 8;
  int i = blockIdx.x * 1024 + threadIdx.x;
  int v = 0;
  if (i < NB8) { int b = i >> 3, x = i & 7; v = cnt8[x * NB + b]; }
  s[threadIdx.x] = v;
  __syncthreads();
  for (int o = 1; o < 1024; o <<= 1) {
    int t = (threadIdx.x >= o) ? s[threadIdx.x - o] : 0;
    __syncthreads();
    s[threadIdx.x] += t;
    __syncthreads();
  }
  if (i < NB8) boffs8[i] = s[threadIdx.x] - v;   // block-local exclusive
  if (threadIdx.x == 1023) ssum[blockIdx.x] = s[1023];
}

__global__ __launch_bounds__(1024) void scanB(int* __restrict__ ssum, int nsb) {
  __shared__ int s[1024];
  int v = (threadIdx.x < nsb) ? ssum[threadIdx.x] : 0;
  s[threadIdx.x] = v;
  __syncthreads();
  for (int o = 1; o < 1024; o <<= 1) {
    int t = (threadIdx.x >= o) ? s[threadIdx.x - o] : 0;
    __syncthreads();
    s[threadIdx.x] += t;
    __syncthreads();
  }
  if (threadIdx.x < nsb) ssum[threadIdx.x] = s[threadIdx.x] - v;
}

// add block sums; also initialize the pass-2 cursors (stripe-major layout)
__global__ __launch_bounds__(1024) void scanC(int* __restrict__ boffs8,
                                              int* __restrict__ bcur8,
                                              const int* __restrict__ ssum, int NB) {
  int NB8 = NB * 8;
  int i = blockIdx.x * 1024 + threadIdx.x;
  if (i < NB8) {
    int v = boffs8[i] + ssum[blockIdx.x];
    boffs8[i] = v;
    int b = i >> 3, x = i & 7;
    bcur8[x * NB + b] = v;
  }
}

// pass 2: scatter packed (dst_local<<27 | src) into stripe-affine sub-segments
__global__ void pass2_scatter(const int* __restrict__ src, const int* __restrict__ dst,
                              int* __restrict__ bcur8, int* __restrict__ tmp,
                              int NB, int E) {
  int e = blockIdx.x * 256 + threadIdx.x;
  if (e >= E) return;
  int x = blockIdx.x & 7;
  int s = src[e], d = dst[e];
  int b = d >> BSH;
  int pos = atomicAdd(&bcur8[x * NB + b], 1);
  tmp[pos] = ((d & (BNODES - 1)) << 27) | s;
}

// per-bucket: local count -> cnt/dis/offs, then reorder into final csrc
__global__ __launch_bounds__(64) void order_kernel(const int* __restrict__ tmp,
    const int* __restrict__ boffs8,
    int* __restrict__ csrc, int* __restrict__ cnt, float* __restrict__ dis,
    int* __restrict__ offs, int NB, int N, int E) {
  __shared__ int lcnt[BNODES];
  __shared__ int lcur[BNODES];
  __shared__ int lofs[BNODES];
  int b = blockIdx.x;
  int lane = threadIdx.x;
  int seg_start = boffs8[b * 8];
  int seg_end = (b + 1 < NB) ? boffs8[(b + 1) * 8] : E;
  int m = seg_end - seg_start;
  if (lane < BNODES) lcnt[lane] = 0;
  __syncthreads();
  for (int idx = lane; idx < m; idx += 64)
    atomicAdd(&lcnt[tmp[seg_start + idx] >> 27], 1);
  __syncthreads();
  if (lane == 0) {
    int run = seg_start;
    for (int k = 0; k < BNODES; ++k) { lofs[k] = run; lcur[k] = run; run += lcnt[k]; }
  }
  __syncthreads();
  int node0 = b << BSH;
  if (lane < BNODES) {
    int node = node0 + lane;
    if (node < N) {
      int c = lcnt[lane];
      cnt[node] = c;
      dis[node] = rsqrtf((float)c + 1.0f);
      offs[node] = lofs[lane];
    }
  }
  for (int idx = lane; idx < m; idx += 64) {
    int rec = tmp[seg_start + idx];
    int pos = atomicAdd(&lcur[rec >> 27], 1);
    csrc[pos] = rec & ((1 << 27) - 1);
  }
}

// ============ f32 GEMM, f16 output: C16[M,128] = A[M,128] @ B[128,128] ============
#define MT 64
#define KC 64
__global__ __launch_bounds__(256) void gemm128_f16out(const float* __restrict__ A,
                                                      const float* __restrict__ B,
                                                      __half* __restrict__ C, int M) {
  __shared__ float sA[MT][KC + 4];
  __shared__ float sB[KC][128];
  int tid = threadIdx.x;
  int m0 = blockIdx.x * MT;
  int tr = tid >> 4;   // 0..15
  int tc = tid & 15;   // 0..15
  float acc[4][8];
#pragma unroll
  for (int i = 0; i < 4; ++i)
#pragma unroll
    for (int j = 0; j < 8; ++j) acc[i][j] = 0.f;

  for (int k0 = 0; k0 < 128; k0 += KC) {
#pragma unroll
    for (int q = 0; q < 4; ++q) {
      int idx = q * 256 + tid;
      int r = idx >> 4;
      int kk = (idx & 15) << 2;
      float4 v = make_float4(0.f, 0.f, 0.f, 0.f);
      if (m0 + r < M) v = *(const float4*)(A + (size_t)(m0 + r) * 128 + k0 + kk);
      *(float4*)(&sA[r][kk]) = v;
    }
#pragma unroll
    for (int q = 0; q < 8; ++q) {
      int idx = q * 256 + tid;
      int kk = idx >> 5;
      int nn = (idx & 31) << 2;
      *(float4*)(&sB[kk][nn]) = *(const float4*)(B + (size_t)(k0 + kk) * 128 + nn);
    }
    __syncthreads();
#pragma unroll 2
    for (int k = 0; k < KC; k += 4) {
      float4 a0 = *(const float4*)(&sA[tr][k]);
      float4 a1 = *(const float4*)(&sA[tr + 16][k]);
      float4 a2 = *(const float4*)(&sA[tr + 32][k]);
      float4 a3 = *(const float4*)(&sA[tr + 48][k]);
#pragma unroll
      for (int u = 0; u < 4; ++u) {
        float4 blo = *(const float4*)(&sB[k + u][tc * 4]);
        float4 bhi = *(const float4*)(&sB[k + u][64 + tc * 4]);
        float av[4] = {((const float*)&a0)[u], ((const float*)&a1)[u],
                       ((const float*)&a2)[u], ((const float*)&a3)[u]};
        float bl[8] = {blo.x, blo.y, blo.z, blo.w, bhi.x, bhi.y, bhi.z, bhi.w};
#pragma unroll
        for (int i = 0; i < 4; ++i)
#pragma unroll
          for (int j = 0; j < 8; ++j) acc[i][j] = fmaf(av[i], bl[j], acc[i][j]);
      }
    }
    __syncthreads();
  }
#pragma unroll
  for (int i = 0; i < 4; ++i) {
    int r = m0 + tr + 16 * i;
    if (r < M) {
      __half2 p0 = __floats2half2_rn(acc[i][0], acc[i][1]);
      __half2 p1 = __floats2half2_rn(acc[i][2], acc[i][3]);
      __half2 p2 = __floats2half2_rn(acc[i][4], acc[i][5]);
      __half2 p3 = __floats2half2_rn(acc[i][6], acc[i][7]);
      __half2* dst0 = (__half2*)(C + (size_t)r * 128 + tc * 4);
      __half2* dst1 = (__half2*)(C + (size_t)r * 128 + 64 + tc * 4);
      dst0[0] = p0; dst0[1] = p1;
      dst1[0] = p2; dst1[1] = p3;
    }
  }
}

// ============ aggregation (f16 gather, f32 accumulate, weight on the fly) ============
__global__ __launch_bounds__(256) void agg_kernel(const __half* __restrict__ h,
    const int* __restrict__ csrc,
    const int* __restrict__ offs, const int* __restrict__ cnt,
    const float* __restrict__ dis, const float* __restrict__ bias,
    float* __restrict__ out, int n) {
  int wave = threadIdx.x >> 6;
  int lane = threadIdx.x & 63;
  int i = blockIdx.x * 4 + wave;
  if (i >= n) return;
  int c = lane * 2;
  int start = offs[i];
  int m = cnt[i];
  float di = dis[i];
  float ax = 0.f, ay = 0.f;
  int e = 0;
  for (; e + 4 <= m; e += 4) {
    int s0 = csrc[start + e];
    int s1 = csrc[start + e + 1];
    int s2 = csrc[start + e + 2];
    int s3 = csrc[start + e + 3];
    float w0 = dis[s0] * di, w1 = dis[s1] * di;
    float w2 = dis[s2] * di, w3 = dis[s3] * di;
    float2 h0 = __half22float2(*(const __half2*)(h + (size_t)s0 * 128 + c));
    float2 h1 = __half22float2(*(const __half2*)(h + (size_t)s1 * 128 + c));
    float2 h2 = __half22float2(*(const __half2*)(h + (size_t)s2 * 128 + c));
    float2 h3 = __half22float2(*(const __half2*)(h + (size_t)s3 * 128 + c));
    ax = fmaf(h0.x, w0, ax); ay = fmaf(h0.y, w0, ay);
    ax = fmaf(h1.x, w1, ax); ay = fmaf(h1.y, w1, ay);
    ax = fmaf(h2.x, w2, ax); ay = fmaf(h2.y, w2, ay);
    ax = fmaf(h3.x, w3, ax); ay = fmaf(h3.y, w3, ay);
  }
  for (; e < m; ++e) {
    int s0 = csrc[start + e];
    float w0 = dis[s0] * di;
    float2 h0 = __half22float2(*(const __half2*)(h + (size_t)s0 * 128 + c));
    ax = fmaf(h0.x, w0, ax); ay = fmaf(h0.y, w0, ay);
  }
  float d2 = di * di;
  float2 hs = __half22float2(*(const __half2*)(h + (size_t)i * 128 + c));
  float2 bv = *(const float2*)(bias + c);
  float vx = fmaf(hs.x, d2, ax) + bv.x;
  float vy = fmaf(hs.y, d2, ay) + bv.y;
  *(float2*)(out + (size_t)i * 128 + c) = make_float2(fmaxf(vx, 0.f), fmaxf(vy, 0.f));
}

// ============ heads: pack 3x[128,20] weights into [128,64] (cols 60..63 zero) ============
__global__ void pack_heads_w(const float* __restrict__ piW, const float* __restrict__ muW,
                             const float* __restrict__ lsW, float* __restrict__ W64) {
  int i = blockIdx.x * 256 + threadIdx.x;
  if (i >= 128 * 64) return;
  int k = i >> 6, j = i & 63;
  float v = 0.f;
  if (j < 20)      v = piW[k * 20 + j];
  else if (j < 40) v = muW[k * 20 + (j - 20)];
  else if (j < 60) v = lsW[k * 20 + (j - 40)];
  W64[i] = v;
}

// ============ heads GEMM: out60[M,64] = A[M,128] @ W64[128,64] ============
__global__ __launch_bounds__(256) void gemm_heads(const float* __restrict__ A,
                                                  const float* __restrict__ B,
                                                  float* __restrict__ C, int M) {
  __shared__ float sA[64][KC + 4];
  __shared__ float sB[KC][68];
  int tid = threadIdx.x;
  int m0 = blockIdx.x * 64;
  int tr = tid >> 4;   // 0..15
  int tc = tid & 15;   // 0..15
  float acc[4][4];
#pragma unroll
  for (int i = 0; i < 4; ++i)
#pragma unroll
    for (int j = 0; j < 4; ++j) acc[i][j] = 0.f;

  for (int k0 = 0; k0 < 128; k0 += KC) {
#pragma unroll
    for (int q = 0; q < 4; ++q) {            // A tile: 64 rows x 64 k
      int idx = q * 256 + tid;
      int r = idx >> 4;
      int kk = (idx & 15) << 2;
      float4 v = make_float4(0.f, 0.f, 0.f, 0.f);
      if (m0 + r < M) v = *(const float4*)(A + (size_t)(m0 + r) * 128 + k0 + kk);
      *(float4*)(&sA[r][kk]) = v;
    }
#pragma unroll
    for (int q = 0; q < 4; ++q) {            // B tile: 64 k x 64 n
      int idx = q * 256 + tid;
      int kk = idx >> 4;
      int nn = (idx & 15) << 2;
      *(float4*)(&sB[kk][nn]) = *(const float4*)(B + (size_t)(k0 + kk) * 64 + nn);
    }
    __syncthreads();
#pragma unroll 4
    for (int k = 0; k < KC; k += 4) {
      float4 a0 = *(const float4*)(&sA[tr][k]);
      float4 a1 = *(const float4*)(&sA[tr + 16][k]);
      float4 a2 = *(const float4*)(&sA[tr + 32][k]);
      float4 a3 = *(const float4*)(&sA[tr + 48][k]);
#pragma unroll
      for (int u = 0; u < 4; ++u) {
        float4 b = *(const float4*)(&sB[k + u][tc * 4]);
        float av[4] = {((const float*)&a0)[u], ((const float*)&a1)[u],
                       ((const float*)&a2)[u], ((const float*)&a3)[u]};
#pragma unroll
        for (int i = 0; i < 4; ++i) {
          acc[i][0] = fmaf(av[i], b.x, acc[i][0]);
          acc[i][1] = fmaf(av[i], b.y, acc[i][1]);
          acc[i][2] = fmaf(av[i], b.z, acc[i][2]);
          acc[i][3] = fmaf(av[i], b.w, acc[i][3]);
        }
      }
    }
    __syncthreads();
  }
#pragma unroll
  for (int i = 0; i < 4; ++i) {
    int r = m0 + tr + 16 * i;
    if (r < M)
      *(float4*)(C + (size_t)r * 64 + tc * 4) =
          make_float4(acc[i][0], acc[i][1], acc[i][2], acc[i][3]);
  }
}

// ============ heads postpass: bias + softmax(20) + scatter ============
__global__ __launch_bounds__(256) void heads_post(const float* __restrict__ out60,
    const float* __restrict__ pib, const float* __restrict__ mub,
    const float* __restrict__ lsb, float* __restrict__ out, int n) {
  int wave = threadIdx.x >> 6, lane = threadIdx.x & 63;
  int node = blockIdx.x * 4 + wave;
  if (node >= n) return;
  float v = 0.f;
  if (lane < 60) {
    v = out60[(size_t)node * 64 + lane];
    v += (lane < 20) ? pib[lane] : (lane < 40) ? mub[lane - 20] : lsb[lane - 40];
  }
  float pv = (lane < 20) ? v : -__builtin_inff();
  float mx = pv;
  for (int o = 16; o > 0; o >>= 1) mx = fmaxf(mx, __shfl_down(mx, o, 32));
  mx = __shfl(mx, 0, 32);
  float ev = (lane < 20) ? expf(v - mx) : 0.f;
  float sm = ev;
  for (int o = 16; o > 0; o >>= 1) sm += __shfl_down(sm, o, 32);
  sm = __shfl(sm, 0, 32);

  size_t base = (size_t)n * NG;
  if (lane < 20)      out[(size_t)node * NG + lane] = ev / sm;
  else if (lane < 40) out[base + (size_t)node * NG + (lane - 20)] = v;
  else if (lane < 60) out[2 * base + (size_t)node * NG + (lane - 40)] = v;
}

extern "C" void kernel_launch(void* const* d_in, const int* in_sizes, int n_in,
                              void* d_out, int out_size, void* d_ws, size_t ws_size,
                              hipStream_t stream) {
  const float* x   = (const float*)d_in[0];
  const int*   ei  = (const int*)d_in[1];
  const float* W1  = (const float*)d_in[2];
  const float* b1  = (const float*)d_in[3];
  const float* W2  = (const float*)d_in[4];
  const float* b2  = (const float*)d_in[5];
  const float* piW = (const float*)d_in[6];
  const float* pib = (const float*)d_in[7];
  const float* muW = (const float*)d_in[8];
  const float* mub = (const float*)d_in[9];
  const float* lsW = (const float*)d_in[10];
  const float* lsb = (const float*)d_in[11];
  float* out = (float*)d_out;

  const int N = in_sizes[0] / IN_DIM;
  const int E = in_sizes[1] / 2;
  const int* src = ei;
  const int* dst = ei + E;

  const int NB  = (N + BNODES - 1) >> BSH;   // 12500
  const int NB8 = NB * 8;
  const int nsb = (NB8 + 1023) / 1024;       // 98

  // workspace layout (~92 MB)
  char* p = (char*)d_ws;
  // region H: h16 [N,128] f16 during layers; out60 [N,64] f32 after agg2 (same bytes)
  char* regionH = p;                        p += (size_t)N * HID * sizeof(__half);
  __half* h16  = (__half*)regionH;
  float* out60 = (float*)regionH;
  // regionR: tmp [E] ints during build, then bufB [N,128] f32 (tmp dead before agg1)
  char* regionR = p;
  size_t szR = (size_t)N * HID * sizeof(float);
  size_t szT = (size_t)E * sizeof(int);
  p += (szR > szT ? szR : szT);
  int*   tmp    = (int*)regionR;
  float* bufB   = (float*)regionR;
  int*   csrc   = (int*)p;                  p += (size_t)E * sizeof(int);
  int*   cnt8   = (int*)p;                  p += (size_t)NB8 * sizeof(int);
  int*   bcur8  = (int*)p;                  p += (size_t)NB8 * sizeof(int);
  int*   boffs8 = (int*)p;                  p += (size_t)NB8 * sizeof(int);
  int*   ssum   = (int*)p;                  p += (size_t)((nsb + 3) & ~3) * sizeof(int);
  int*   cnt    = (int*)p;                  p += (size_t)N * sizeof(int);
  int*   offs   = (int*)p;                  p += (size_t)N * sizeof(int);
  float* dis    = (float*)p;                p += (size_t)N * sizeof(float);
  float* W64    = (float*)p;                p += (size_t)128 * 64 * sizeof(float);

  // ---- CSR build ----
  zero_ints<<<(NB8 + 255) / 256, 256, 0, stream>>>(cnt8, NB8);
  pass1_count<<<(E + 255) / 256, 256, 0, stream>>>(dst, cnt8, NB, E);
  scanA<<<nsb, 1024, 0, stream>>>(cnt8, boffs8, ssum, NB);
  scanB<<<1, 1024, 0, stream>>>(ssum, nsb);
  scanC<<<nsb, 1024, 0, stream>>>(boffs8, bcur8, ssum, NB);
  pass2_scatter<<<(E + 255) / 256, 256, 0, stream>>>(src, dst, bcur8, tmp, NB, E);
  order_kernel<<<NB, 64, 0, stream>>>(tmp, boffs8, csrc, cnt, dis, offs, NB, N, E);
  pack_heads_w<<<(128 * 64 + 255) / 256, 256, 0, stream>>>(piW, muW, lsW, W64);

  // ---- layers ----
  gemm128_f16out<<<(N + MT - 1) / MT, 256, 0, stream>>>(x, W1, h16, N);
  agg_kernel<<<(N + 3) / 4, 256, 0, stream>>>(h16, csrc, offs, cnt, dis, b1, bufB, N);
  gemm128_f16out<<<(N + MT - 1) / MT, 256, 0, stream>>>(bufB, W2, h16, N);
  agg_kernel<<<(N + 3) / 4, 256, 0, stream>>>(h16, csrc, offs, cnt, dis, b2, bufB, N);

  // ---- heads: GEMM + postpass (out60 aliases h16, dead after agg2) ----
  gemm_heads<<<(N + 63) / 64, 256, 0, stream>>>(bufB, W64, out60, N);
  heads_post<<<(N + 3) / 4, 256, 0, stream>>>(out60, pib, mub, lsb, out, N);
}

// Round 7
// 612.549 us; speedup vs baseline: 1.9307x; 1.2972x over previous
//
#include <hip/hip_runtime.h>
#include <hip/hip_fp16.h>
#include <cstdint>
#include <cstddef>

#define IN_DIM 128
#define HID    128
#define NG     20
#define T      4096        // edges per binsort1 block
#define MAXB   400         // max coarse bins (N <= 102400)

__global__ void zero_ints(int* __restrict__ a, int n) {
  int i = blockIdx.x * blockDim.x + threadIdx.x;
  if (i < n) a[i] = 0;
}

// ============ level 1: block-local sort into coarse bins (256 nodes/bin) ============
// Per block: histogram tile in LDS -> scan -> reorder in LDS -> coalesced stream-out.
// All global writes are sequential full lines (no scatter).
__global__ __launch_bounds__(256) void binsort1(const int* __restrict__ src,
    const int* __restrict__ dst, int* __restrict__ tmp, int* __restrict__ bofs,
    int* __restrict__ bintot, int NBC, int E) {
  __shared__ int lhist[MAXB];
  __shared__ int lscan[512];
  __shared__ int lcur[MAXB];
  __shared__ int sbuf[T];
  int tid = threadIdx.x;
  int tile0 = blockIdx.x * T;
  int m = E - tile0; if (m > T) m = T;

  for (int i = tid; i < NBC; i += 256) lhist[i] = 0;
  __syncthreads();

  int dreg[16];
#pragma unroll
  for (int j = 0; j < 16; ++j) {
    int idx = j * 256 + tid;
    dreg[j] = -1;
    if (idx < m) {
      int d = dst[tile0 + idx];
      dreg[j] = d;
      atomicAdd(&lhist[d >> 8], 1);
    }
  }
  __syncthreads();

  // exclusive scan over NBC (<=400) padded to 512, 2 elems/thread
  int v0 = (tid < NBC) ? lhist[tid] : 0;
  int v1 = (256 + tid < NBC) ? lhist[256 + tid] : 0;
  lscan[tid] = v0; lscan[256 + tid] = v1;
  __syncthreads();
  for (int o = 1; o < 512; o <<= 1) {
    int a0 = (tid >= o) ? lscan[tid - o] : 0;
    int a1 = (256 + tid >= o) ? lscan[256 + tid - o] : 0;
    __syncthreads();
    lscan[tid] += a0; lscan[256 + tid] += a1;
    __syncthreads();
  }
  if (tid < NBC)       lcur[tid]       = lscan[tid] - v0;
  if (256 + tid < NBC) lcur[256 + tid] = lscan[256 + tid] - v1;
  __syncthreads();

  // per-(block,bin) starts + sentinel; bin totals
  int ST = NBC + 1;
  for (int i = tid; i < NBC; i += 256) bofs[(size_t)blockIdx.x * ST + i] = lcur[i];
  if (tid == 0) bofs[(size_t)blockIdx.x * ST + NBC] = m;
  for (int i = tid; i < NBC; i += 256)
    if (lhist[i]) atomicAdd(&bintot[i], lhist[i]);
  __syncthreads();

  // placement into LDS (bin-grouped), record = (dst&255)<<17 | src  (src < 2^17)
#pragma unroll
  for (int j = 0; j < 16; ++j) {
    int idx = j * 256 + tid;
    if (idx < m) {
      int d = dreg[j];
      int s = src[tile0 + idx];
      int slot = atomicAdd(&lcur[d >> 8], 1);
      sbuf[slot] = ((d & 255) << 17) | s;
    }
  }
  __syncthreads();

  // coalesced stream-out
  int nv = m >> 2;
  int4* out4 = (int4*)(tmp + tile0);
  const int4* sb4 = (const int4*)sbuf;
  for (int i = tid; i < nv; i += 256) out4[i] = sb4[i];
  for (int i = (nv << 2) + tid; i < m; i += 256) tmp[tile0 + i] = sbuf[i];
}

// ============ scan bin totals -> bin bases (1 block) ============
__global__ __launch_bounds__(512) void binscan(const int* __restrict__ bintot,
                                               int* __restrict__ binbase, int NBC) {
  __shared__ int s[512];
  int tid = threadIdx.x;
  int v = (tid < NBC) ? bintot[tid] : 0;
  s[tid] = v;
  __syncthreads();
  for (int o = 1; o < 512; o <<= 1) {
    int t = (tid >= o) ? s[tid - o] : 0;
    __syncthreads();
    s[tid] += t;
    __syncthreads();
  }
  if (tid < NBC) binbase[tid] = s[tid] - v;
}

// ============ level 2: one block per coarse bin -> final CSR + node meta ============
// Reads its records from the 782 block-regions (L3-hot), scatters only within its
// own exclusive csrc window (lines become fully dirty while L2-resident).
__global__ __launch_bounds__(512) void binsort2(const int* __restrict__ tmp,
    const int* __restrict__ bofs, const int* __restrict__ binbase,
    int* __restrict__ csrc, int* __restrict__ cnt, float* __restrict__ dis,
    int* __restrict__ offs, int NBC, int nblk, int N) {
  __shared__ int lcnt[256];
  __shared__ int lsc[256];
  __shared__ int lcur2[256];
  int b = blockIdx.x;
  int tid = threadIdx.x;
  if (tid < 256) lcnt[tid] = 0;
  __syncthreads();
  int ST = NBC + 1;
  for (int r = tid; r < nblk; r += 512) {
    int s = bofs[(size_t)r * ST + b];
    int e2 = bofs[(size_t)r * ST + b + 1];
    int base = r * T;
    for (int k = s; k < e2; ++k)
      atomicAdd(&lcnt[tmp[base + k] >> 17], 1);
  }
  __syncthreads();
  if (tid < 256) lsc[tid] = lcnt[tid];
  __syncthreads();
  for (int o = 1; o < 256; o <<= 1) {
    int t = 0;
    if (tid < 256 && tid >= o) t = lsc[tid - o];
    __syncthreads();
    if (tid < 256) lsc[tid] += t;
    __syncthreads();
  }
  int gbase = binbase[b];
  if (tid < 256) {
    int excl = lsc[tid] - lcnt[tid];
    lcur2[tid] = gbase + excl;
    int node = (b << 8) + tid;
    if (node < N) {
      cnt[node] = lcnt[tid];
      dis[node] = rsqrtf((float)lcnt[tid] + 1.0f);
      offs[node] = gbase + excl;
    }
  }
  __syncthreads();
  for (int r = tid; r < nblk; r += 512) {
    int s = bofs[(size_t)r * ST + b];
    int e2 = bofs[(size_t)r * ST + b + 1];
    int base = r * T;
    for (int k = s; k < e2; ++k) {
      int rec = tmp[base + k];
      int pos = atomicAdd(&lcur2[rec >> 17], 1);
      csrc[pos] = rec & 0x1FFFF;
    }
  }
}

// ============ f32 GEMM, f16 output: C16[M,128] = A[M,128] @ B[128,128] ============
#define MT 64
#define KC 64
__global__ __launch_bounds__(256) void gemm128_f16out(const float* __restrict__ A,
                                                      const float* __restrict__ B,
                                                      __half* __restrict__ C, int M) {
  __shared__ float sA[MT][KC + 4];
  __shared__ float sB[KC][128];
  int tid = threadIdx.x;
  int m0 = blockIdx.x * MT;
  int tr = tid >> 4;   // 0..15
  int tc = tid & 15;   // 0..15
  float acc[4][8];
#pragma unroll
  for (int i = 0; i < 4; ++i)
#pragma unroll
    for (int j = 0; j < 8; ++j) acc[i][j] = 0.f;

  for (int k0 = 0; k0 < 128; k0 += KC) {
#pragma unroll
    for (int q = 0; q < 4; ++q) {
      int idx = q * 256 + tid;
      int r = idx >> 4;
      int kk = (idx & 15) << 2;
      float4 v = make_float4(0.f, 0.f, 0.f, 0.f);
      if (m0 + r < M) v = *(const float4*)(A + (size_t)(m0 + r) * 128 + k0 + kk);
      *(float4*)(&sA[r][kk]) = v;
    }
#pragma unroll
    for (int q = 0; q < 8; ++q) {
      int idx = q * 256 + tid;
      int kk = idx >> 5;
      int nn = (idx & 31) << 2;
      *(float4*)(&sB[kk][nn]) = *(const float4*)(B + (size_t)(k0 + kk) * 128 + nn);
    }
    __syncthreads();
#pragma unroll 2
    for (int k = 0; k < KC; k += 4) {
      float4 a0 = *(const float4*)(&sA[tr][k]);
      float4 a1 = *(const float4*)(&sA[tr + 16][k]);
      float4 a2 = *(const float4*)(&sA[tr + 32][k]);
      float4 a3 = *(const float4*)(&sA[tr + 48][k]);
#pragma unroll
      for (int u = 0; u < 4; ++u) {
        float4 blo = *(const float4*)(&sB[k + u][tc * 4]);
        float4 bhi = *(const float4*)(&sB[k + u][64 + tc * 4]);
        float av[4] = {((const float*)&a0)[u], ((const float*)&a1)[u],
                       ((const float*)&a2)[u], ((const float*)&a3)[u]};
        float bl[8] = {blo.x, blo.y, blo.z, blo.w, bhi.x, bhi.y, bhi.z, bhi.w};
#pragma unroll
        for (int i = 0; i < 4; ++i)
#pragma unroll
          for (int j = 0; j < 8; ++j) acc[i][j] = fmaf(av[i], bl[j], acc[i][j]);
      }
    }
    __syncthreads();
  }
#pragma unroll
  for (int i = 0; i < 4; ++i) {
    int r = m0 + tr + 16 * i;
    if (r < M) {
      __half2 p0 = __floats2half2_rn(acc[i][0], acc[i][1]);
      __half2 p1 = __floats2half2_rn(acc[i][2], acc[i][3]);
      __half2 p2 = __floats2half2_rn(acc[i][4], acc[i][5]);
      __half2 p3 = __floats2half2_rn(acc[i][6], acc[i][7]);
      __half2* dst0 = (__half2*)(C + (size_t)r * 128 + tc * 4);
      __half2* dst1 = (__half2*)(C + (size_t)r * 128 + 64 + tc * 4);
      dst0[0] = p0; dst0[1] = p1;
      dst1[0] = p2; dst1[1] = p3;
    }
  }
}

// ============ aggregation (f16 gather, f32 accumulate, weight on the fly) ============
__global__ __launch_bounds__(256) void agg_kernel(const __half* __restrict__ h,
    const int* __restrict__ csrc,
    const int* __restrict__ offs, const int* __restrict__ cnt,
    const float* __restrict__ dis, const float* __restrict__ bias,
    float* __restrict__ out, int n) {
  int wave = threadIdx.x >> 6;
  int lane = threadIdx.x & 63;
  int i = blockIdx.x * 4 + wave;
  if (i >= n) return;
  int c = lane * 2;
  int start = offs[i];
  int m = cnt[i];
  float di = dis[i];
  float ax = 0.f, ay = 0.f;
  int e = 0;
  for (; e + 4 <= m; e += 4) {
    int s0 = csrc[start + e];
    int s1 = csrc[start + e + 1];
    int s2 = csrc[start + e + 2];
    int s3 = csrc[start + e + 3];
    float w0 = dis[s0] * di, w1 = dis[s1] * di;
    float w2 = dis[s2] * di, w3 = dis[s3] * di;
    float2 h0 = __half22float2(*(const __half2*)(h + (size_t)s0 * 128 + c));
    float2 h1 = __half22float2(*(const __half2*)(h + (size_t)s1 * 128 + c));
    float2 h2 = __half22float2(*(const __half2*)(h + (size_t)s2 * 128 + c));
    float2 h3 = __half22float2(*(const __half2*)(h + (size_t)s3 * 128 + c));
    ax = fmaf(h0.x, w0, ax); ay = fmaf(h0.y, w0, ay);
    ax = fmaf(h1.x, w1, ax); ay = fmaf(h1.y, w1, ay);
    ax = fmaf(h2.x, w2, ax); ay = fmaf(h2.y, w2, ay);
    ax = fmaf(h3.x, w3, ax); ay = fmaf(h3.y, w3, ay);
  }
  for (; e < m; ++e) {
    int s0 = csrc[start + e];
    float w0 = dis[s0] * di;
    float2 h0 = __half22float2(*(const __half2*)(h + (size_t)s0 * 128 + c));
    ax = fmaf(h0.x, w0, ax); ay = fmaf(h0.y, w0, ay);
  }
  float d2 = di * di;
  float2 hs = __half22float2(*(const __half2*)(h + (size_t)i * 128 + c));
  float2 bv = *(const float2*)(bias + c);
  float vx = fmaf(hs.x, d2, ax) + bv.x;
  float vy = fmaf(hs.y, d2, ay) + bv.y;
  *(float2*)(out + (size_t)i * 128 + c) = make_float2(fmaxf(vx, 0.f), fmaxf(vy, 0.f));
}

// ============ heads: pack 3x[128,20] weights into [128,64] (cols 60..63 zero) ============
__global__ void pack_heads_w(const float* __restrict__ piW, const float* __restrict__ muW,
                             const float* __restrict__ lsW, float* __restrict__ W64) {
  int i = blockIdx.x * 256 + threadIdx.x;
  if (i >= 128 * 64) return;
  int k = i >> 6, j = i & 63;
  float v = 0.f;
  if (j < 20)      v = piW[k * 20 + j];
  else if (j < 40) v = muW[k * 20 + (j - 20)];
  else if (j < 60) v = lsW[k * 20 + (j - 40)];
  W64[i] = v;
}

// ============ heads GEMM: out60[M,64] = A[M,128] @ W64[128,64] ============
__global__ __launch_bounds__(256) void gemm_heads(const float* __restrict__ A,
                                                  const float* __restrict__ B,
                                                  float* __restrict__ C, int M) {
  __shared__ float sA[64][KC + 4];
  __shared__ float sB[KC][68];
  int tid = threadIdx.x;
  int m0 = blockIdx.x * 64;
  int tr = tid >> 4;   // 0..15
  int tc = tid & 15;   // 0..15
  float acc[4][4];
#pragma unroll
  for (int i = 0; i < 4; ++i)
#pragma unroll
    for (int j = 0; j < 4; ++j) acc[i][j] = 0.f;

  for (int k0 = 0; k0 < 128; k0 += KC) {
#pragma unroll
    for (int q = 0; q < 4; ++q) {
      int idx = q * 256 + tid;
      int r = idx >> 4;
      int kk = (idx & 15) << 2;
      float4 v = make_float4(0.f, 0.f, 0.f, 0.f);
      if (m0 + r < M) v = *(const float4*)(A + (size_t)(m0 + r) * 128 + k0 + kk);
      *(float4*)(&sA[r][kk]) = v;
    }
#pragma unroll
    for (int q = 0; q < 4; ++q) {
      int idx = q * 256 + tid;
      int kk = idx >> 4;
      int nn = (idx & 15) << 2;
      *(float4*)(&sB[kk][nn]) = *(const float4*)(B + (size_t)(k0 + kk) * 64 + nn);
    }
    __syncthreads();
#pragma unroll 4
    for (int k = 0; k < KC; k += 4) {
      float4 a0 = *(const float4*)(&sA[tr][k]);
      float4 a1 = *(const float4*)(&sA[tr + 16][k]);
      float4 a2 = *(const float4*)(&sA[tr + 32][k]);
      float4 a3 = *(const float4*)(&sA[tr + 48][k]);
#pragma unroll
      for (int u = 0; u < 4; ++u) {
        float4 b = *(const float4*)(&sB[k + u][tc * 4]);
        float av[4] = {((const float*)&a0)[u], ((const float*)&a1)[u],
                       ((const float*)&a2)[u], ((const float*)&a3)[u]};
#pragma unroll
        for (int i = 0; i < 4; ++i) {
          acc[i][0] = fmaf(av[i], b.x, acc[i][0]);
          acc[i][1] = fmaf(av[i], b.y, acc[i][1]);
          acc[i][2] = fmaf(av[i], b.z, acc[i][2]);
          acc[i][3] = fmaf(av[i], b.w, acc[i][3]);
        }
      }
    }
    __syncthreads();
  }
#pragma unroll
  for (int i = 0; i < 4; ++i) {
    int r = m0 + tr + 16 * i;
    if (r < M)
      *(float4*)(C + (size_t)r * 64 + tc * 4) =
          make_float4(acc[i][0], acc[i][1], acc[i][2], acc[i][3]);
  }
}

// ============ heads postpass: bias + softmax(20) + scatter ============
__global__ __launch_bounds__(256) void heads_post(const float* __restrict__ out60,
    const float* __restrict__ pib, const float* __restrict__ mub,
    const float* __restrict__ lsb, float* __restrict__ out, int n) {
  int wave = threadIdx.x >> 6, lane = threadIdx.x & 63;
  int node = blockIdx.x * 4 + wave;
  if (node >= n) return;
  float v = 0.f;
  if (lane < 60) {
    v = out60[(size_t)node * 64 + lane];
    v += (lane < 20) ? pib[lane] : (lane < 40) ? mub[lane - 20] : lsb[lane - 40];
  }
  float pv = (lane < 20) ? v : -__builtin_inff();
  float mx = pv;
  for (int o = 16; o > 0; o >>= 1) mx = fmaxf(mx, __shfl_down(mx, o, 32));
  mx = __shfl(mx, 0, 32);
  float ev = (lane < 20) ? expf(v - mx) : 0.f;
  float sm = ev;
  for (int o = 16; o > 0; o >>= 1) sm += __shfl_down(sm, o, 32);
  sm = __shfl(sm, 0, 32);

  size_t base = (size_t)n * NG;
  if (lane < 20)      out[(size_t)node * NG + lane] = ev / sm;
  else if (lane < 40) out[base + (size_t)node * NG + (lane - 20)] = v;
  else if (lane < 60) out[2 * base + (size_t)node * NG + (lane - 40)] = v;
}

extern "C" void kernel_launch(void* const* d_in, const int* in_sizes, int n_in,
                              void* d_out, int out_size, void* d_ws, size_t ws_size,
                              hipStream_t stream) {
  const float* x   = (const float*)d_in[0];
  const int*   ei  = (const int*)d_in[1];
  const float* W1  = (const float*)d_in[2];
  const float* b1  = (const float*)d_in[3];
  const float* W2  = (const float*)d_in[4];
  const float* b2  = (const float*)d_in[5];
  const float* piW = (const float*)d_in[6];
  const float* pib = (const float*)d_in[7];
  const float* muW = (const float*)d_in[8];
  const float* mub = (const float*)d_in[9];
  const float* lsW = (const float*)d_in[10];
  const float* lsb = (const float*)d_in[11];
  float* out = (float*)d_out;

  const int N = in_sizes[0] / IN_DIM;
  const int E = in_sizes[1] / 2;
  const int* src = ei;
  const int* dst = ei + E;

  const int NBC  = (N + 255) >> 8;          // 391 coarse bins
  const int nblk = (E + T - 1) / T;         // 782 level-1 blocks
  const int ST   = NBC + 1;

  // workspace layout (~70 MB)
  char* p = (char*)d_ws;
  // region H: h16 [N,128] f16 during layers; out60 [N,64] f32 for heads
  char* regionH = p;                        p += (size_t)N * HID * sizeof(__half);
  __half* h16  = (__half*)regionH;
  float* out60 = (float*)regionH;
  // regionR: tmp [E] ints during build, then bufB [N,128] f32
  char* regionR = p;
  size_t szR = (size_t)N * HID * sizeof(float);
  size_t szT = (size_t)E * sizeof(int);
  p += (szR > szT ? szR : szT);
  int*   tmp    = (int*)regionR;
  float* bufB   = (float*)regionR;
  int*   csrc   = (int*)p;                  p += (size_t)E * sizeof(int);
  int*   bofs   = (int*)p;                  p += (size_t)nblk * ST * sizeof(int);
  int*   bintot = (int*)p;                  p += (size_t)MAXB * sizeof(int);
  int*   binbase= (int*)p;                  p += (size_t)MAXB * sizeof(int);
  int*   cnt    = (int*)p;                  p += (size_t)N * sizeof(int);
  int*   offs   = (int*)p;                  p += (size_t)N * sizeof(int);
  float* dis    = (float*)p;                p += (size_t)N * sizeof(float);
  float* W64    = (float*)p;                p += (size_t)128 * 64 * sizeof(float);

  // ---- CSR build (block-local sort; all writes coalesced or block-exclusive) ----
  zero_ints<<<(NBC + 255) / 256, 256, 0, stream>>>(bintot, NBC);
  binsort1<<<nblk, 256, 0, stream>>>(src, dst, tmp, bofs, bintot, NBC, E);
  binscan<<<1, 512, 0, stream>>>(bintot, binbase, NBC);
  binsort2<<<NBC, 512, 0, stream>>>(tmp, bofs, binbase, csrc, cnt, dis, offs,
                                    NBC, nblk, N);
  pack_heads_w<<<(128 * 64 + 255) / 256, 256, 0, stream>>>(piW, muW, lsW, W64);

  // ---- layers ----
  gemm128_f16out<<<(N + MT - 1) / MT, 256, 0, stream>>>(x, W1, h16, N);
  agg_kernel<<<(N + 3) / 4, 256, 0, stream>>>(h16, csrc, offs, cnt, dis, b1, bufB, N);
  gemm128_f16out<<<(N + MT - 1) / MT, 256, 0, stream>>>(bufB, W2, h16, N);
  agg_kernel<<<(N + 3) / 4, 256, 0, stream>>>(h16, csrc, offs, cnt, dis, b2, bufB, N);

  // ---- heads ----
  gemm_heads<<<(N + 63) / 64, 256, 0, stream>>>(bufB, W64, out60, N);
  heads_post<<<(N + 3) / 4, 256, 0, stream>>>(out60, pib, mub, lsb, out, N);
}

// Round 8
// 594.056 us; speedup vs baseline: 1.9908x; 1.0311x over previous
//
#include <hip/hip_runtime.h>
#include <hip/hip_fp16.h>
#include <cstdint>
#include <cstddef>

#define IN_DIM 128
#define HID    128
#define NG     20
#define T      4096        // edges per binsort1 block
#define MAXB   400         // max coarse bins (N <= 102400)

__global__ void zero_ints(int* __restrict__ a, int n) {
  int i = blockIdx.x * blockDim.x + threadIdx.x;
  if (i < n) a[i] = 0;
}

// ============ level 1: block-local sort into coarse bins (256 nodes/bin) ============
__global__ __launch_bounds__(256) void binsort1(const int* __restrict__ src,
    const int* __restrict__ dst, int* __restrict__ tmp, int* __restrict__ bofs,
    int* __restrict__ bintot, int NBC, int E) {
  __shared__ int lhist[MAXB];
  __shared__ int lscan[512];
  __shared__ int lcur[MAXB];
  __shared__ int sbuf[T];
  int tid = threadIdx.x;
  int tile0 = blockIdx.x * T;
  int m = E - tile0; if (m > T) m = T;

  for (int i = tid; i < NBC; i += 256) lhist[i] = 0;
  __syncthreads();

  int dreg[16];
#pragma unroll
  for (int j = 0; j < 16; ++j) {
    int idx = j * 256 + tid;
    dreg[j] = -1;
    if (idx < m) {
      int d = dst[tile0 + idx];
      dreg[j] = d;
      atomicAdd(&lhist[d >> 8], 1);
    }
  }
  __syncthreads();

  int v0 = (tid < NBC) ? lhist[tid] : 0;
  int v1 = (256 + tid < NBC) ? lhist[256 + tid] : 0;
  lscan[tid] = v0; lscan[256 + tid] = v1;
  __syncthreads();
  for (int o = 1; o < 512; o <<= 1) {
    int a0 = (tid >= o) ? lscan[tid - o] : 0;
    int a1 = (256 + tid >= o) ? lscan[256 + tid - o] : 0;
    __syncthreads();
    lscan[tid] += a0; lscan[256 + tid] += a1;
    __syncthreads();
  }
  if (tid < NBC)       lcur[tid]       = lscan[tid] - v0;
  if (256 + tid < NBC) lcur[256 + tid] = lscan[256 + tid] - v1;
  __syncthreads();

  int ST = NBC + 1;
  for (int i = tid; i < NBC; i += 256) bofs[(size_t)blockIdx.x * ST + i] = lcur[i];
  if (tid == 0) bofs[(size_t)blockIdx.x * ST + NBC] = m;
  for (int i = tid; i < NBC; i += 256)
    if (lhist[i]) atomicAdd(&bintot[i], lhist[i]);
  __syncthreads();

#pragma unroll
  for (int j = 0; j < 16; ++j) {
    int idx = j * 256 + tid;
    if (idx < m) {
      int d = dreg[j];
      int s = src[tile0 + idx];
      int slot = atomicAdd(&lcur[d >> 8], 1);
      sbuf[slot] = ((d & 255) << 17) | s;
    }
  }
  __syncthreads();

  int nv = m >> 2;
  int4* out4 = (int4*)(tmp + tile0);
  const int4* sb4 = (const int4*)sbuf;
  for (int i = tid; i < nv; i += 256) out4[i] = sb4[i];
  for (int i = (nv << 2) + tid; i < m; i += 256) tmp[tile0 + i] = sbuf[i];
}

// ============ scan bin totals -> bin bases (1 block) ============
__global__ __launch_bounds__(512) void binscan(const int* __restrict__ bintot,
                                               int* __restrict__ binbase, int NBC) {
  __shared__ int s[512];
  int tid = threadIdx.x;
  int v = (tid < NBC) ? bintot[tid] : 0;
  s[tid] = v;
  __syncthreads();
  for (int o = 1; o < 512; o <<= 1) {
    int t = (tid >= o) ? s[tid - o] : 0;
    __syncthreads();
    s[tid] += t;
    __syncthreads();
  }
  if (tid < NBC) binbase[tid] = s[tid] - v;
}

// ============ level 2: one block per coarse bin -> final CSR + node meta ============
__global__ __launch_bounds__(512) void binsort2(const int* __restrict__ tmp,
    const int* __restrict__ bofs, const int* __restrict__ binbase,
    int* __restrict__ csrc, int* __restrict__ cnt, float* __restrict__ dis,
    int* __restrict__ offs, int NBC, int nblk, int N) {
  __shared__ int lcnt[256];
  __shared__ int lsc[256];
  __shared__ int lcur2[256];
  int b = blockIdx.x;
  int tid = threadIdx.x;
  if (tid < 256) lcnt[tid] = 0;
  __syncthreads();
  int ST = NBC + 1;
  for (int r = tid; r < nblk; r += 512) {
    int s = bofs[(size_t)r * ST + b];
    int e2 = bofs[(size_t)r * ST + b + 1];
    int base = r * T;
    for (int k = s; k < e2; ++k)
      atomicAdd(&lcnt[tmp[base + k] >> 17], 1);
  }
  __syncthreads();
  if (tid < 256) lsc[tid] = lcnt[tid];
  __syncthreads();
  for (int o = 1; o < 256; o <<= 1) {
    int t = 0;
    if (tid < 256 && tid >= o) t = lsc[tid - o];
    __syncthreads();
    if (tid < 256) lsc[tid] += t;
    __syncthreads();
  }
  int gbase = binbase[b];
  if (tid < 256) {
    int excl = lsc[tid] - lcnt[tid];
    lcur2[tid] = gbase + excl;
    int node = (b << 8) + tid;
    if (node < N) {
      cnt[node] = lcnt[tid];
      dis[node] = rsqrtf((float)lcnt[tid] + 1.0f);
      offs[node] = gbase + excl;
    }
  }
  __syncthreads();
  for (int r = tid; r < nblk; r += 512) {
    int s = bofs[(size_t)r * ST + b];
    int e2 = bofs[(size_t)r * ST + b + 1];
    int base = r * T;
    for (int k = s; k < e2; ++k) {
      int rec = tmp[base + k];
      int pos = atomicAdd(&lcur2[rec >> 17], 1);
      csrc[pos] = rec & 0x1FFFF;
    }
  }
}

// ============ f32 GEMM, f16 output: C16[M,128] = A[M,128] @ B[128,128] ============
#define MT 64
#define KC 64
__global__ __launch_bounds__(256) void gemm128_f16out(const float* __restrict__ A,
                                                      const float* __restrict__ B,
                                                      __half* __restrict__ C, int M) {
  __shared__ float sA[MT][KC + 4];
  __shared__ float sB[KC][128];
  int tid = threadIdx.x;
  int m0 = blockIdx.x * MT;
  int tr = tid >> 4;   // 0..15
  int tc = tid & 15;   // 0..15
  float acc[4][8];
#pragma unroll
  for (int i = 0; i < 4; ++i)
#pragma unroll
    for (int j = 0; j < 8; ++j) acc[i][j] = 0.f;

  for (int k0 = 0; k0 < 128; k0 += KC) {
#pragma unroll
    for (int q = 0; q < 4; ++q) {
      int idx = q * 256 + tid;
      int r = idx >> 4;
      int kk = (idx & 15) << 2;
      float4 v = make_float4(0.f, 0.f, 0.f, 0.f);
      if (m0 + r < M) v = *(const float4*)(A + (size_t)(m0 + r) * 128 + k0 + kk);
      *(float4*)(&sA[r][kk]) = v;
    }
#pragma unroll
    for (int q = 0; q < 8; ++q) {
      int idx = q * 256 + tid;
      int kk = idx >> 5;
      int nn = (idx & 31) << 2;
      *(float4*)(&sB[kk][nn]) = *(const float4*)(B + (size_t)(k0 + kk) * 128 + nn);
    }
    __syncthreads();
#pragma unroll 2
    for (int k = 0; k < KC; k += 4) {
      float4 a0 = *(const float4*)(&sA[tr][k]);
      float4 a1 = *(const float4*)(&sA[tr + 16][k]);
      float4 a2 = *(const float4*)(&sA[tr + 32][k]);
      float4 a3 = *(const float4*)(&sA[tr + 48][k]);
#pragma unroll
      for (int u = 0; u < 4; ++u) {
        float4 blo = *(const float4*)(&sB[k + u][tc * 4]);
        float4 bhi = *(const float4*)(&sB[k + u][64 + tc * 4]);
        float av[4] = {((const float*)&a0)[u], ((const float*)&a1)[u],
                       ((const float*)&a2)[u], ((const float*)&a3)[u]};
        float bl[8] = {blo.x, blo.y, blo.z, blo.w, bhi.x, bhi.y, bhi.z, bhi.w};
#pragma unroll
        for (int i = 0; i < 4; ++i)
#pragma unroll
          for (int j = 0; j < 8; ++j) acc[i][j] = fmaf(av[i], bl[j], acc[i][j]);
      }
    }
    __syncthreads();
  }
#pragma unroll
  for (int i = 0; i < 4; ++i) {
    int r = m0 + tr + 16 * i;
    if (r < M) {
      __half2 p0 = __floats2half2_rn(acc[i][0], acc[i][1]);
      __half2 p1 = __floats2half2_rn(acc[i][2], acc[i][3]);
      __half2 p2 = __floats2half2_rn(acc[i][4], acc[i][5]);
      __half2 p3 = __floats2half2_rn(acc[i][6], acc[i][7]);
      __half2* dst0 = (__half2*)(C + (size_t)r * 128 + tc * 4);
      __half2* dst1 = (__half2*)(C + (size_t)r * 128 + 64 + tc * 4);
      dst0[0] = p0; dst0[1] = p1;
      dst1[0] = p2; dst1[1] = p3;
    }
  }
}

// ============ aggregation v2: lane-parallel (s,w) staging + readlane broadcast ============
// out[i] = relu(sum_e h16[src_e]*w_e + h16[i]*dis_i^2 + b)
__global__ __launch_bounds__(256) void agg_kernel(const __half* __restrict__ h,
    const int* __restrict__ csrc,
    const int* __restrict__ offs, const int* __restrict__ cnt,
    const float* __restrict__ dis, const float* __restrict__ bias,
    float* __restrict__ out, int n) {
  int wave = threadIdx.x >> 6;
  int lane = threadIdx.x & 63;
  int i = blockIdx.x * 4 + wave;
  if (i >= n) return;
  int c = lane * 2;
  int start = offs[i];
  int m = cnt[i];
  float di = dis[i];
  float ax = 0.f, ay = 0.f;

  for (int base = 0; base < m; base += 64) {
    int mc = m - base; if (mc > 64) mc = 64;
    // lane-parallel staging: coalesced index load + parallel dis gather
    int   sj = 0;
    float wj = 0.f;
    if (lane < mc) {
      sj = csrc[start + base + lane];
      wj = dis[sj] * di;
    }
    int j = 0;
    for (; j + 4 <= mc; j += 4) {
      int   s0 = __shfl(sj, j);
      int   s1 = __shfl(sj, j + 1);
      int   s2 = __shfl(sj, j + 2);
      int   s3 = __shfl(sj, j + 3);
      float w0 = __shfl(wj, j);
      float w1 = __shfl(wj, j + 1);
      float w2 = __shfl(wj, j + 2);
      float w3 = __shfl(wj, j + 3);
      float2 h0 = __half22float2(*(const __half2*)(h + (size_t)s0 * 128 + c));
      float2 h1 = __half22float2(*(const __half2*)(h + (size_t)s1 * 128 + c));
      float2 h2 = __half22float2(*(const __half2*)(h + (size_t)s2 * 128 + c));
      float2 h3 = __half22float2(*(const __half2*)(h + (size_t)s3 * 128 + c));
      ax = fmaf(h0.x, w0, ax); ay = fmaf(h0.y, w0, ay);
      ax = fmaf(h1.x, w1, ax); ay = fmaf(h1.y, w1, ay);
      ax = fmaf(h2.x, w2, ax); ay = fmaf(h2.y, w2, ay);
      ax = fmaf(h3.x, w3, ax); ay = fmaf(h3.y, w3, ay);
    }
    for (; j < mc; ++j) {
      int   s0 = __shfl(sj, j);
      float w0 = __shfl(wj, j);
      float2 h0 = __half22float2(*(const __half2*)(h + (size_t)s0 * 128 + c));
      ax = fmaf(h0.x, w0, ax); ay = fmaf(h0.y, w0, ay);
    }
  }
  float d2 = di * di;
  float2 hs = __half22float2(*(const __half2*)(h + (size_t)i * 128 + c));
  float2 bv = *(const float2*)(bias + c);
  float vx = fmaf(hs.x, d2, ax) + bv.x;
  float vy = fmaf(hs.y, d2, ay) + bv.y;
  *(float2*)(out + (size_t)i * 128 + c) = make_float2(fmaxf(vx, 0.f), fmaxf(vy, 0.f));
}

// ============ heads: pack 3x[128,20] weights into [128,64] (cols 60..63 zero) ============
__global__ void pack_heads_w(const float* __restrict__ piW, const float* __restrict__ muW,
                             const float* __restrict__ lsW, float* __restrict__ W64) {
  int i = blockIdx.x * 256 + threadIdx.x;
  if (i >= 128 * 64) return;
  int k = i >> 6, j = i & 63;
  float v = 0.f;
  if (j < 20)      v = piW[k * 20 + j];
  else if (j < 40) v = muW[k * 20 + (j - 20)];
  else if (j < 60) v = lsW[k * 20 + (j - 40)];
  W64[i] = v;
}

// ============ heads GEMM: out60[M,64] = A[M,128] @ W64[128,64] ============
__global__ __launch_bounds__(256) void gemm_heads(const float* __restrict__ A,
                                                  const float* __restrict__ B,
                                                  float* __restrict__ C, int M) {
  __shared__ float sA[64][KC + 4];
  __shared__ float sB[KC][68];
  int tid = threadIdx.x;
  int m0 = blockIdx.x * 64;
  int tr = tid >> 4;   // 0..15
  int tc = tid & 15;   // 0..15
  float acc[4][4];
#pragma unroll
  for (int i = 0; i < 4; ++i)
#pragma unroll
    for (int j = 0; j < 4; ++j) acc[i][j] = 0.f;

  for (int k0 = 0; k0 < 128; k0 += KC) {
#pragma unroll
    for (int q = 0; q < 4; ++q) {
      int idx = q * 256 + tid;
      int r = idx >> 4;
      int kk = (idx & 15) << 2;
      float4 v = make_float4(0.f, 0.f, 0.f, 0.f);
      if (m0 + r < M) v = *(const float4*)(A + (size_t)(m0 + r) * 128 + k0 + kk);
      *(float4*)(&sA[r][kk]) = v;
    }
#pragma unroll
    for (int q = 0; q < 4; ++q) {
      int idx = q * 256 + tid;
      int kk = idx >> 4;
      int nn = (idx & 15) << 2;
      *(float4*)(&sB[kk][nn]) = *(const float4*)(B + (size_t)(k0 + kk) * 64 + nn);
    }
    __syncthreads();
#pragma unroll 4
    for (int k = 0; k < KC; k += 4) {
      float4 a0 = *(const float4*)(&sA[tr][k]);
      float4 a1 = *(const float4*)(&sA[tr + 16][k]);
      float4 a2 = *(const float4*)(&sA[tr + 32][k]);
      float4 a3 = *(const float4*)(&sA[tr + 48][k]);
#pragma unroll
      for (int u = 0; u < 4; ++u) {
        float4 b = *(const float4*)(&sB[k + u][tc * 4]);
        float av[4] = {((const float*)&a0)[u], ((const float*)&a1)[u],
                       ((const float*)&a2)[u], ((const float*)&a3)[u]};
#pragma unroll
        for (int i = 0; i < 4; ++i) {
          acc[i][0] = fmaf(av[i], b.x, acc[i][0]);
          acc[i][1] = fmaf(av[i], b.y, acc[i][1]);
          acc[i][2] = fmaf(av[i], b.z, acc[i][2]);
          acc[i][3] = fmaf(av[i], b.w, acc[i][3]);
        }
      }
    }
    __syncthreads();
  }
#pragma unroll
  for (int i = 0; i < 4; ++i) {
    int r = m0 + tr + 16 * i;
    if (r < M)
      *(float4*)(C + (size_t)r * 64 + tc * 4) =
          make_float4(acc[i][0], acc[i][1], acc[i][2], acc[i][3]);
  }
}

// ============ heads postpass: bias + softmax(20) + scatter ============
__global__ __launch_bounds__(256) void heads_post(const float* __restrict__ out60,
    const float* __restrict__ pib, const float* __restrict__ mub,
    const float* __restrict__ lsb, float* __restrict__ out, int n) {
  int wave = threadIdx.x >> 6, lane = threadIdx.x & 63;
  int node = blockIdx.x * 4 + wave;
  if (node >= n) return;
  float v = 0.f;
  if (lane < 60) {
    v = out60[(size_t)node * 64 + lane];
    v += (lane < 20) ? pib[lane] : (lane < 40) ? mub[lane - 20] : lsb[lane - 40];
  }
  float pv = (lane < 20) ? v : -__builtin_inff();
  float mx = pv;
  for (int o = 16; o > 0; o >>= 1) mx = fmaxf(mx, __shfl_down(mx, o, 32));
  mx = __shfl(mx, 0, 32);
  float ev = (lane < 20) ? expf(v - mx) : 0.f;
  float sm = ev;
  for (int o = 16; o > 0; o >>= 1) sm += __shfl_down(sm, o, 32);
  sm = __shfl(sm, 0, 32);

  size_t base = (size_t)n * NG;
  if (lane < 20)      out[(size_t)node * NG + lane] = ev / sm;
  else if (lane < 40) out[base + (size_t)node * NG + (lane - 20)] = v;
  else if (lane < 60) out[2 * base + (size_t)node * NG + (lane - 40)] = v;
}

extern "C" void kernel_launch(void* const* d_in, const int* in_sizes, int n_in,
                              void* d_out, int out_size, void* d_ws, size_t ws_size,
                              hipStream_t stream) {
  const float* x   = (const float*)d_in[0];
  const int*   ei  = (const int*)d_in[1];
  const float* W1  = (const float*)d_in[2];
  const float* b1  = (const float*)d_in[3];
  const float* W2  = (const float*)d_in[4];
  const float* b2  = (const float*)d_in[5];
  const float* piW = (const float*)d_in[6];
  const float* pib = (const float*)d_in[7];
  const float* muW = (const float*)d_in[8];
  const float* mub = (const float*)d_in[9];
  const float* lsW = (const float*)d_in[10];
  const float* lsb = (const float*)d_in[11];
  float* out = (float*)d_out;

  const int N = in_sizes[0] / IN_DIM;
  const int E = in_sizes[1] / 2;
  const int* src = ei;
  const int* dst = ei + E;

  const int NBC  = (N + 255) >> 8;          // 391 coarse bins
  const int nblk = (E + T - 1) / T;         // 782 level-1 blocks
  const int ST   = NBC + 1;

  // workspace layout (~70 MB)
  char* p = (char*)d_ws;
  char* regionH = p;                        p += (size_t)N * HID * sizeof(__half);
  __half* h16  = (__half*)regionH;
  float* out60 = (float*)regionH;
  char* regionR = p;
  size_t szR = (size_t)N * HID * sizeof(float);
  size_t szT = (size_t)E * sizeof(int);
  p += (szR > szT ? szR : szT);
  int*   tmp    = (int*)regionR;
  float* bufB   = (float*)regionR;
  int*   csrc   = (int*)p;                  p += (size_t)E * sizeof(int);
  int*   bofs   = (int*)p;                  p += (size_t)nblk * ST * sizeof(int);
  int*   bintot = (int*)p;                  p += (size_t)MAXB * sizeof(int);
  int*   binbase= (int*)p;                  p += (size_t)MAXB * sizeof(int);
  int*   cnt    = (int*)p;                  p += (size_t)N * sizeof(int);
  int*   offs   = (int*)p;                  p += (size_t)N * sizeof(int);
  float* dis    = (float*)p;                p += (size_t)N * sizeof(float);
  float* W64    = (float*)p;                p += (size_t)128 * 64 * sizeof(float);

  // ---- CSR build ----
  zero_ints<<<(NBC + 255) / 256, 256, 0, stream>>>(bintot, NBC);
  binsort1<<<nblk, 256, 0, stream>>>(src, dst, tmp, bofs, bintot, NBC, E);
  binscan<<<1, 512, 0, stream>>>(bintot, binbase, NBC);
  binsort2<<<NBC, 512, 0, stream>>>(tmp, bofs, binbase, csrc, cnt, dis, offs,
                                    NBC, nblk, N);
  pack_heads_w<<<(128 * 64 + 255) / 256, 256, 0, stream>>>(piW, muW, lsW, W64);

  // ---- layers ----
  gemm128_f16out<<<(N + MT - 1) / MT, 256, 0, stream>>>(x, W1, h16, N);
  agg_kernel<<<(N + 3) / 4, 256, 0, stream>>>(h16, csrc, offs, cnt, dis, b1, bufB, N);
  gemm128_f16out<<<(N + MT - 1) / MT, 256, 0, stream>>>(bufB, W2, h16, N);
  agg_kernel<<<(N + 3) / 4, 256, 0, stream>>>(h16, csrc, offs, cnt, dis, b2, bufB, N);

  // ---- heads ----
  gemm_heads<<<(N + 63) / 64, 256, 0, stream>>>(bufB, W64, out60, N);
  heads_post<<<(N + 3) / 4, 256, 0, stream>>>(out60, pib, mub, lsb, out, N);
}